// Round 9
// baseline (189.227 us; speedup 1.0000x reference)
//
#include <hip/hip_runtime.h>
#include <hip/hip_bf16.h>
#include <cstdint>
#include <cstddef>

// Problem constants
#define B_   2
#define S_   2048
#define H_   1024
#define NH   16
#define DH   64
#define LOG2E 1.4426950408889634f
#define SCALE2 (0.125f * LOG2E)   // D^-0.5 * log2(e): softmax done in exp2 domain
#define CUMPAD 132                // zero-pad floats before cum row (min gidx -130)
#define CUMROW (CUMPAD + S_)      // 2180 floats per head row

typedef __hip_bfloat16 bf16;
typedef short bf16x8 __attribute__((ext_vector_type(8)));   // 8 bf16 in 4 VGPRs
typedef float f32x4 __attribute__((ext_vector_type(4)));
typedef f32x4 __attribute__((aligned(4))) f32x4u;           // 4B-aligned vector load

#define MFMA16(a, b, c) __builtin_amdgcn_mfma_f32_16x16x32_bf16((a), (b), (c), 0, 0, 0)

__device__ __forceinline__ void async16(const void* g, void* l) {
  __builtin_amdgcn_global_load_lds(
      (const __attribute__((address_space(1))) void*)g,
      (__attribute__((address_space(3))) void*)l,
      16, 0, 0);
}

__device__ __forceinline__ short bf16bits(float v) {
  bf16 t = __float2bfloat16(v);
  return *reinterpret_cast<short*>(&t);
}

// ---------------------------------------------------------------------------
// Fused prep kernel (one dispatch, grid 8208). R9: cum rows padded with
// CUMPAD zero floats so fa can read bias quads directly from global
// (unaligned f32x4; indices down to -130 land in the pad).
// ---------------------------------------------------------------------------
__device__ __forceinline__ void tr_body(const float* __restrict__ src,
                                        bf16* __restrict__ dst, int R, int C,
                                        int c0, int r0, bf16 (*tile)[33], int tid) {
  int tx = tid & 31, ty = tid >> 5;   // 32 x 8
  for (int i = 0; i < 32; i += 8)
    tile[ty + i][tx] = __float2bfloat16(src[(size_t)(r0 + ty + i) * C + c0 + tx]);
  __syncthreads();
  for (int i = 0; i < 32; i += 8)
    dst[(size_t)(c0 + ty + i) * R + r0 + tx] = tile[tx][ty + i];
}

__global__ __launch_bounds__(256)
void prep(const float* __restrict__ x, bf16* __restrict__ xb,
          const float* __restrict__ qkv, bf16* __restrict__ qkvT,
          const float* __restrict__ outw, bf16* __restrict__ outwT,
          const float* __restrict__ rpe, float* __restrict__ cum) {
  __shared__ char pm[2176] __attribute__((aligned(16)));
  const int L = blockIdx.x, tid = threadIdx.x;
  if (L < 4096) {
    int i = (L * 256 + tid) * 4;
    float4 v = *(const float4*)(x + i);
    bf16 o[4] = {__float2bfloat16(v.x), __float2bfloat16(v.y),
                 __float2bfloat16(v.z), __float2bfloat16(v.w)};
    *(uint64_t*)(xb + i) = *(const uint64_t*)o;
  } else if (L < 7168) {
    int t = L - 4096;
    int cx = t % 96, ry = t / 96;
    tr_body(qkv, qkvT, 1024, 3072, cx * 32, ry * 32, (bf16(*)[33])pm, tid);
  } else if (L < 8192) {
    int t = L - 7168;
    int cx = t & 31, ry = t >> 5;
    tr_body(outw, outwT, 1024, 1024, cx * 32, ry * 32, (bf16(*)[33])pm, tid);
  } else {
    // rpe cumsum (scaled by LOG2E) into padded row
    float* ssum = (float*)pm;
    int n = L - 8192;
    float* crow = cum + (size_t)n * CUMROW;
    if (tid < CUMPAD) crow[tid] = 0.f;          // zero the pad
    float loc[8];
    float s = 0.f;
    int base = tid * 8;
#pragma unroll
    for (int u = 0; u < 8; ++u) {
      loc[u] = rpe[n * S_ + base + u];
      s += loc[u];
    }
    ssum[tid] = s;
    __syncthreads();
    float own = s;
    for (int off = 1; off < 256; off <<= 1) {
      float v = (tid >= off) ? ssum[tid - off] : 0.f;
      __syncthreads();
      ssum[tid] += v;
      __syncthreads();
    }
    float run = ssum[tid] - own;   // exclusive prefix of this thread's chunk
#pragma unroll
    for (int u = 0; u < 8; ++u) {
      run += loc[u];
      crow[CUMPAD + base + u] = run * LOG2E;
    }
  }
}

// ---------------------------------------------------------------------------
// GEMM — unchanged from R8 (dbuf single-barrier; measured neutral but kept).
// ---------------------------------------------------------------------------
template <int MODE>
__global__ __launch_bounds__(256, MODE == 0 ? 3 : 2)
void gemm_bt(const bf16* __restrict__ A, const bf16* __restrict__ Bt,
             bf16* __restrict__ C0, bf16* __restrict__ C1, bf16* __restrict__ C2,
             float* __restrict__ F0) {
  constexpr int NT = (MODE == 0) ? 4 : 2;     // n-subtiles per wave
  constexpr int NB = NT * 32;                 // block n-extent: 128 or 64
  constexpr int BUFSZ = 8192 + NB * 64;       // A 8KB + B NB*32*2B
  __shared__ char smem[MODE == 0 ? 36864 : 24576] __attribute__((aligned(16)));
  const int tid = threadIdx.x, lane = tid & 63, w = tid >> 6;
  const int lr = lane & 15, lq = lane >> 4;
  const int m0 = blockIdx.y * 128, n0 = blockIdx.x * NB;
  const int wm = (w & 1) * 64, wn = (w >> 1) * (NT * 16);

  f32x4 acc[4][NT] = {};

  auto stage = [&](int buf, int k0) {
    char* dst = smem + buf * BUFSZ;
#pragma unroll
    for (int t = 0; t < 2; ++t) {
      int c = t * 256 + tid;
      int row = c >> 2, ch = c & 3;
      int k8 = (ch ^ ((row >> 1) & 3)) * 8;
      async16(A + (size_t)(m0 + row) * 1024 + k0 + k8, dst + c * 16);
    }
#pragma unroll
    for (int t = 0; t < NB / 64; ++t) {
      int c = t * 256 + tid;
      int row = c >> 2, ch = c & 3;
      int k8 = (ch ^ ((row >> 1) & 3)) * 8;
      async16(Bt + (size_t)(n0 + row) * 1024 + k0 + k8, dst + 8192 + c * 16);
    }
  };

  stage(0, 0);

  for (int s = 0; s < 32; ++s) {
    const int bsel = s & 1;
    __syncthreads();
    if (s + 1 < 32) stage(bsel ^ 1, (s + 1) * 32);

    const bf16* As = (const bf16*)(smem + bsel * BUFSZ);
    const bf16* Bs = (const bf16*)(smem + bsel * BUFSZ + 8192);
    bf16x8 af[4], bfr[NT];
#pragma unroll
    for (int mt = 0; mt < 4; ++mt) {
      int row = wm + mt * 16 + lr;
      af[mt] = *(const bf16x8*)(As + row * 32 + ((lq ^ ((row >> 1) & 3)) << 3));
    }
#pragma unroll
    for (int nt = 0; nt < NT; ++nt) {
      int row = wn + nt * 16 + lr;
      bfr[nt] = *(const bf16x8*)(Bs + row * 32 + ((lq ^ ((row >> 1) & 3)) << 3));
    }
#pragma unroll
    for (int mt = 0; mt < 4; ++mt)
#pragma unroll
      for (int nt = 0; nt < NT; ++nt)
        acc[mt][nt] = MFMA16(af[mt], bfr[nt], acc[mt][nt]);
  }

  if (MODE == 0) {
    __syncthreads();   // all As/Bs reads done; reuse LDS for epilogue tiles
    bf16* E = (bf16*)smem + w * (64 * 72);   // wave-private [64][72]
    const int cbase = n0 + wn;               // 64-aligned
    const int mm = cbase >> 10, nn = (cbase >> 6) & 15;
    const int bb = (m0 + wm) >> 11;
    const int sbase = (m0 + wm) & 2047;
    if (mm < 2) {
#pragma unroll
      for (int mt = 0; mt < 4; ++mt)
#pragma unroll
        for (int nt = 0; nt < 4; ++nt)
#pragma unroll
          for (int r = 0; r < 4; ++r)
            E[(mt * 16 + lq * 4 + r) * 72 + nt * 16 + lr] =
                __float2bfloat16(acc[mt][nt][r]);
      bf16* dst = (mm == 0 ? C0 : C1) +
                  ((size_t)(bb * NH + nn) * S_ + sbase) * DH;
#pragma unroll
      for (int it = 0; it < 8; ++it) {
        int c = it * 64 + lane;
        int rw = c >> 3, c8 = c & 7;
        *(uint4*)(dst + (size_t)rw * DH + c8 * 8) =
            *(const uint4*)(E + rw * 72 + c8 * 8);
      }
    } else {
#pragma unroll
      for (int mt = 0; mt < 4; ++mt)
#pragma unroll
        for (int nt = 0; nt < 4; ++nt)
#pragma unroll
          for (int r = 0; r < 4; ++r)
            E[(nt * 16 + lr) * 72 + mt * 16 + lq * 4 + r] =
                __float2bfloat16(acc[mt][nt][r]);
      bf16* dst = C2 + (size_t)(bb * NH + nn) * DH * S_;
#pragma unroll
      for (int it = 0; it < 8; ++it) {
        int c = it * 64 + lane;
        int dr = c >> 3, c8 = c & 7;
        *(uint4*)(dst + (size_t)dr * S_ + sbase + c8 * 8) =
            *(const uint4*)(E + dr * 72 + c8 * 8);
      }
    }
  } else {
#pragma unroll
    for (int mt = 0; mt < 4; ++mt)
#pragma unroll
      for (int nt = 0; nt < NT; ++nt)
#pragma unroll
        for (int r = 0; r < 4; ++r) {
          int rM = m0 + wm + mt * 16 + lq * 4 + r;
          int cN = n0 + wn + nt * 16 + lr;
          F0[(size_t)rM * 1024 + cN] = acc[mt][nt][r];
        }
  }
}

// ---------------------------------------------------------------------------
// Flash attention, R9: fa is LDS-BANDWIDTH-bound (R7 counters: 24 b128
// reads/wave/unit = ~1500 of 1800 cyc/unit at 128B/cyc; MfmaUtil 15%,
// VALUBusy 45%). Two cuts:
//  1. 4-WAY J-SPLIT: wave = 64 Q-rows x 32 j-cols (was 32x64). kf/vf
//     amortize over 4 i-subtiles: 8 b128/wave/unit (4 kf + 4 vf), was 16.
//     Same 36 MFMA/wave/unit. R6 permuted-K in-reg-P carries over per
//     32-col chunk (kkey identical). Tile-end combine = 2-stage pairwise
//     tree through the consumed K/V buffer.
//  2. BIAS FROM GLOBAL: cum rows zero-padded (CUMPAD=132) so bias quads
//     load as unaligned f32x4 from global (L1-resident ~4KB window) —
//     cum LDS staging AND its 8 b128 reads/wave vanish.
// LDS traffic/unit/CU: 192+88KB -> 64+64KB (-55%).
// q,k: [bn][S][D] bf16;  vt: [bn][D][S] bf16;  cum: [N][CUMROW] f32 padded;
// mix out: [b][s][n][d] bf16
// LDS: K/V dbuf [0,65536) (buf b at b*32768: K 16K, V 16K);
//      combL [3][64] f32 [65536,66304). 66304 x 2 blocks/CU <= 160 KB.
// ---------------------------------------------------------------------------
__device__ __forceinline__ void fa_stage(const bf16* __restrict__ k,
                                         const bf16* __restrict__ vt,
                                         char* smem, int bn, int jb,
                                         int buf, int tid) {
  char* dst = smem + buf * 32768;
  // K tile: rows jb..jb+127 (128B each, 8 chunks); slot (row,ch) holds
  // global chunk ch^kk(row), kk = (row&3)|((row>>1)&4). 1024 chunks.
  const char* ksrc = (const char*)(k + ((size_t)bn * S_ + jb) * DH);
#pragma unroll
  for (int t = 0; t < 4; ++t) {
    int c = t * 256 + tid;
    int row = c >> 3, ch = c & 7;
    int cs = ch ^ ((row & 3) | ((row >> 1) & 4));
    async16(ksrc + row * 128 + cs * 16, dst + c * 16);
  }
  // Vt tile: d rows 0..63, cols jb..jb+127 (256B, 16 chunks); slot (d,ch)
  // holds global chunk ch^(d&15). 1024 chunks.
  const char* vsrc = (const char*)(vt + (size_t)bn * DH * S_);
#pragma unroll
  for (int t = 0; t < 4; ++t) {
    int c = t * 256 + tid;
    int row = c >> 4, ch = c & 15;            // row = d index
    int cs = ch ^ (row & 15);
    async16(vsrc + (size_t)row * (S_ * 2) + jb * 2 + cs * 16,
            dst + 16384 + c * 16);
  }
}

__global__ __launch_bounds__(256, 2)
void fa_kernel(const bf16* __restrict__ q, const bf16* __restrict__ k,
               const bf16* __restrict__ vt, const float* __restrict__ cum,
               bf16* __restrict__ mix) {
  __shared__ char smem[66304] __attribute__((aligned(16)));
  float* combL = (float*)(smem + 65536);        // [3][64]

  const int tid = threadIdx.x, lane = tid & 63, w = tid >> 6;  // w = jh: 0..3
  const int lr = lane & 15, lq = lane >> 4;
  const int jh = w;                             // j-quarter (32 cols)

  const int L = blockIdx.x;                     // 0..511
  const int xcd = L & 7, slot = L >> 3;         // slot 0..63
  const int bn = xcd + 8 * (slot & 3);          // 4 heads per XCD
  const int pp = slot >> 2;                     // pair index 0..15
  const int n = bn & (NH - 1);
  const int b = bn >> 4;
  const float* cumnP = cum + (size_t)n * CUMROW + CUMPAD;

  const int T0 = 31 - pp;                       // heavy tile
  const int T1 = pp;                            // light tile
  const int nu0 = (T0 + 2) >> 1;                // units in tile 0

  // all-ones B fragment for the l row-sum MFMA
  bf16x8 ones;
#pragma unroll
  for (int u = 0; u < 8; ++u) ones[u] = (short)0x3F80;
  const f32x4 fz = {0.f, 0.f, 0.f, 0.f};

  // permuted-K swizzle key (independent of kd/nt2/jh)
  const int kkey = (lr & 3) | (((lr >> 2) & 1) << 2);

  bf16x8 qf[4][2];                              // [is][kd]
  f32x4 oacc[4][4];                             // [is][dt]
  f32x4 lacc[4];

  // prologue: stage unit 0 (tile T0, jt 0) into buf 0
  fa_stage(k, vt, smem, bn, 0, 0, tid);

  int jt = 0, i0 = T0 * 64, nu = nu0;

  for (int g = 0; g < 17; ++g) {
    const int bsel = g & 1;
    const char* kb = smem + bsel * 32768;
    const char* vb = kb + 16384;
    const int jb = jt * 128;
    const bool diag = (jt == nu - 1);           // last unit of this tile

    __syncthreads();   // staged data for g visible; buf^1 prior reads done

    // prefetch unit g+1 into the other buffer (flies during this compute)
    if (g + 1 < 17) {
      int gn = g + 1, jtn;
      if (gn < nu0) jtn = gn;
      else          jtn = gn - nu0;
      fa_stage(k, vt, smem, bn, jtn * 128, bsel ^ 1, tid);
    }

    if (jt == 0) {
      // new tile: load Q fragments (B-operand for S^T = K*Q^T), reset acc
      const bf16* qbase = q + ((size_t)bn * S_ + i0) * DH;
#pragma unroll
      for (int is = 0; is < 4; ++is) {
#pragma unroll
        for (int kd = 0; kd < 2; ++kd)
          qf[is][kd] = *(const bf16x8*)(qbase + (is * 16 + lr) * DH + kd * 32 + lq * 8);
        lacc[is] = fz;
#pragma unroll
        for (int dt = 0; dt < 4; ++dt) oacc[is][dt] = fz;
      }
    }

    // S^T = K * Q^T with PERMUTED K rows over this wave's 32-col chunk.
    // A-row lr of MFMA nt2 loads krow = jh*32 + (lr>>2)*8 + nt2*4 + (lr&3),
    // so C position (lq*4+r) holds j = jh*32 + lq*8 + nt2*4 + r — the PV
    // A-fragment layout. kf shared across 4 i-subtiles.
    f32x4 sa[4][2] = {};
#pragma unroll
    for (int kd = 0; kd < 2; ++kd)
#pragma unroll
      for (int nt2 = 0; nt2 < 2; ++nt2) {
        int krow = jh * 32 + ((lr >> 2) << 3) + nt2 * 4 + (lr & 3);
        bf16x8 kf = *(const bf16x8*)(kb + krow * 128 +
                        (((kd * 4 + lq) ^ kkey) << 4));
#pragma unroll
        for (int is = 0; is < 4; ++is)
          sa[is][nt2] = MFMA16(kf, qf[is][kd], sa[is][nt2]);
      }

    // p = exp2(s*SCALE2 + cum[i-j]) straight into PV A-fragments.
    // Bias quad DIRECT FROM GLOBAL (padded row): cv[m] = cum[gidx+m],
    // gidx = doff + ilocI - jl - 3 >= -130 (pad); bias(r) = cv[3-r].
    const int doff = i0 - jb;                   // diag: 0 or 64; else >=128
    bf16x8 pf[4];
#pragma unroll
    for (int is = 0; is < 4; ++is) {
      const int ilocI = is * 16 + lr;           // 0..63
#pragma unroll
      for (int nt2 = 0; nt2 < 2; ++nt2) {
        int jl = jh * 32 + lq * 8 + nt2 * 4;
        int gidx = doff + ilocI - jl - 3;
        f32x4 cv = *(const f32x4u*)(cumnP + gidx);
        if (!diag) {
#pragma unroll
          for (int r = 0; r < 4; ++r)
            pf[is][nt2 * 4 + r] =
                bf16bits(exp2f(sa[is][nt2][r] * SCALE2 + cv[3 - r]));
        } else {
#pragma unroll
          for (int r = 0; r < 4; ++r) {
            float pv = (doff + ilocI - jl - r >= 0)
                           ? exp2f(sa[is][nt2][r] * SCALE2 + cv[3 - r])
                           : 0.f;
            pf[is][nt2 * 4 + r] = bf16bits(pv);
          }
        }
      }
    }

    // O += P V; l += P 1 — pf straight from registers; vf shared across is.
#pragma unroll
    for (int is = 0; is < 4; ++is)
      lacc[is] = MFMA16(pf[is], ones, lacc[is]);
#pragma unroll
    for (int dt = 0; dt < 4; ++dt) {
      int vrow = dt * 16 + lr;
      bf16x8 vf = *(const bf16x8*)(vb + vrow * 256 +
                      (((jh * 4 + lq) ^ (vrow & 15)) << 4));
#pragma unroll
      for (int is = 0; is < 4; ++is)
        oacc[is][dt] = MFMA16(pf[is], vf, oacc[is][dt]);
    }

    if (diag) {
      // tile end: combine the 4 j-quarters (additive — no-max exp2 softmax).
      // 2-stage pairwise tree through the consumed K/V buffer (32KB free).
      __syncthreads();   // all reads of buf bsel complete
      f32x4* scrq = (f32x4*)(smem + bsel * 32768);   // 2048 f32x4
      if (jh == 1 || jh == 3) {
        f32x4* dst = scrq + (jh == 1 ? 0 : 1024);
#pragma unroll
        for (int is = 0; is < 4; ++is)
#pragma unroll
          for (int dt = 0; dt < 4; ++dt)
            dst[(is * 4 + dt) * 64 + lane] = oacc[is][dt];
      }
      if (jh >= 1 && lr == 0) {
#pragma unroll
        for (int is = 0; is < 4; ++is)
#pragma unroll
          for (int r = 0; r < 4; ++r)
            combL[(jh - 1) * 64 + is * 16 + lq * 4 + r] = lacc[is][r];
      }
      __syncthreads();
      if (jh == 0) {
#pragma unroll
        for (int is = 0; is < 4; ++is)
#pragma unroll
          for (int dt = 0; dt < 4; ++dt)
            oacc[is][dt] += scrq[(is * 4 + dt) * 64 + lane];
      } else if (jh == 2) {
#pragma unroll
        for (int is = 0; is < 4; ++is)
#pragma unroll
          for (int dt = 0; dt < 4; ++dt)
            oacc[is][dt] += scrq[1024 + (is * 4 + dt) * 64 + lane];
      }
      __syncthreads();
      if (jh == 2) {
#pragma unroll
        for (int is = 0; is < 4; ++is)
#pragma unroll
          for (int dt = 0; dt < 4; ++dt)
            scrq[(is * 4 + dt) * 64 + lane] = oacc[is][dt];
      }
      __syncthreads();
      if (jh == 0) {
#pragma unroll
        for (int is = 0; is < 4; ++is) {
#pragma unroll
          for (int dt = 0; dt < 4; ++dt)
            oacc[is][dt] += scrq[(is * 4 + dt) * 64 + lane];
#pragma unroll
          for (int r = 0; r < 4; ++r)
            lacc[is][r] += combL[is * 16 + lq * 4 + r] +
                           combL[64 + is * 16 + lq * 4 + r] +
                           combL[128 + is * 16 + lq * 4 + r];
        }
        // store mix[b][s][n][d] for all 64 tile rows
#pragma unroll
        for (int is = 0; is < 4; ++is)
#pragma unroll
          for (int dt = 0; dt < 4; ++dt)
#pragma unroll
            for (int r = 0; r < 4; ++r) {
              int i = i0 + is * 16 + lq * 4 + r;
              int d = dt * 16 + lr;
              mix[((size_t)(b * S_ + i) * NH + n) * DH + d] =
                  __float2bfloat16(oacc[is][dt][r] / lacc[is][r]);
            }
      }
      jt = 0; i0 = T1 * 64; nu = (T1 + 2) >> 1;  // switch to light tile
    } else {
      ++jt;
    }
  }
}

// ---------------------------------------------------------------------------
extern "C" void kernel_launch(void* const* d_in, const int* in_sizes, int n_in,
                              void* d_out, int out_size, void* d_ws, size_t ws_size,
                              hipStream_t stream) {
  const float* x     = (const float*)d_in[0];   // [B,S,H] f32
  const float* qkv   = (const float*)d_in[1];   // [H,3,N,D] f32 == [1024][3072]
  const float* out_w = (const float*)d_in[2];   // [N,D,H] f32   == [1024][1024]
  const float* rpe   = (const float*)d_in[3];   // [N,S] f32
  float* out = (float*)d_out;                   // [B,S,H] f32

  char* ws = (char*)d_ws;
  bf16* qkvT  = (bf16*)(ws + 0);          // [3072][1024] bf16   6291456 B
  bf16* outwT = (bf16*)(ws + 6291456);    // [1024][1024] bf16   2097152 B
  bf16* xb    = (bf16*)(ws + 8388608);    // [4096][1024] bf16   8388608 B
  bf16* qb    = (bf16*)(ws + 16777216);   // [bn][S][D]          8388608 B
  bf16* kb    = (bf16*)(ws + 25165824);   // [bn][S][D]          8388608 B
  bf16* vtb   = (bf16*)(ws + 33554432);   // [bn][D][S]          8388608 B
  bf16* mixb  = (bf16*)(ws + 41943040);   // [b][s][n][d]        8388608 B
  float* cum  = (float*)(ws + 50331648);  // [N][CUMROW] f32      139520 B

  // 1. fused prep: convert x, transpose+convert weights, padded rpe cumsum
  prep<<<8208, 256, 0, stream>>>(x, xb, qkv, qkvT, out_w, outwT, rpe, cum);
  // 2. QKV projection (V written pre-transposed; 768 blocks = 3/CU)
  gemm_bt<0><<<dim3(3072 / 128, 4096 / 128), 256, 0, stream>>>(xb, qkvT, qb, kb, vtb, nullptr);
  // 3. attention: 512 blocks, 17 64x128-units each (pair {31-p, p}),
  //    4-way j-split waves, in-reg P, bias from padded global cum
  fa_kernel<<<512, 256, 0, stream>>>(qb, kb, vtb, cum, mixb);
  // 4. output projection (f32 out; 128x64 tiles -> 512 blocks = 2/CU)
  gemm_bt<1><<<dim3(1024 / 64, 4096 / 128), 256, 0, stream>>>(mixb, outwT, nullptr, nullptr, nullptr, out);
}

// Round 10
// 183.951 us; speedup vs baseline: 1.0287x; 1.0287x over previous
//
#include <hip/hip_runtime.h>
#include <hip/hip_bf16.h>
#include <cstdint>
#include <cstddef>

// Problem constants
#define B_   2
#define S_   2048
#define H_   1024
#define NH   16
#define DH   64
#define LOG2E 1.4426950408889634f
#define SCALE2 (0.125f * LOG2E)   // D^-0.5 * log2(e): softmax done in exp2 domain
#define CUMPAD 132                // zero-pad floats before cum row (min gidx -130)
#define CUMROW (CUMPAD + S_)      // 2180 floats per head row

typedef __hip_bfloat16 bf16;
typedef short bf16x8 __attribute__((ext_vector_type(8)));   // 8 bf16 in 4 VGPRs
typedef float f32x4 __attribute__((ext_vector_type(4)));
typedef f32x4 __attribute__((aligned(4))) f32x4u;           // 4B-aligned vector load

#define MFMA16(a, b, c) __builtin_amdgcn_mfma_f32_16x16x32_bf16((a), (b), (c), 0, 0, 0)

__device__ __forceinline__ void async16(const void* g, void* l) {
  __builtin_amdgcn_global_load_lds(
      (const __attribute__((address_space(1))) void*)g,
      (__attribute__((address_space(3))) void*)l,
      16, 0, 0);
}

__device__ __forceinline__ short bf16bits(float v) {
  bf16 t = __float2bfloat16(v);
  return *reinterpret_cast<short*>(&t);
}

// ---------------------------------------------------------------------------
// Fused prep kernel (one dispatch, grid 8208). cum rows padded with CUMPAD
// zero floats so fa can read bias quads directly from global.
// ---------------------------------------------------------------------------
__device__ __forceinline__ void tr_body(const float* __restrict__ src,
                                        bf16* __restrict__ dst, int R, int C,
                                        int c0, int r0, bf16 (*tile)[33], int tid) {
  int tx = tid & 31, ty = tid >> 5;   // 32 x 8
  for (int i = 0; i < 32; i += 8)
    tile[ty + i][tx] = __float2bfloat16(src[(size_t)(r0 + ty + i) * C + c0 + tx]);
  __syncthreads();
  for (int i = 0; i < 32; i += 8)
    dst[(size_t)(c0 + ty + i) * R + r0 + tx] = tile[tx][ty + i];
}

__global__ __launch_bounds__(256)
void prep(const float* __restrict__ x, bf16* __restrict__ xb,
          const float* __restrict__ qkv, bf16* __restrict__ qkvT,
          const float* __restrict__ outw, bf16* __restrict__ outwT,
          const float* __restrict__ rpe, float* __restrict__ cum) {
  __shared__ char pm[2176] __attribute__((aligned(16)));
  const int L = blockIdx.x, tid = threadIdx.x;
  if (L < 4096) {
    int i = (L * 256 + tid) * 4;
    float4 v = *(const float4*)(x + i);
    bf16 o[4] = {__float2bfloat16(v.x), __float2bfloat16(v.y),
                 __float2bfloat16(v.z), __float2bfloat16(v.w)};
    *(uint64_t*)(xb + i) = *(const uint64_t*)o;
  } else if (L < 7168) {
    int t = L - 4096;
    int cx = t % 96, ry = t / 96;
    tr_body(qkv, qkvT, 1024, 3072, cx * 32, ry * 32, (bf16(*)[33])pm, tid);
  } else if (L < 8192) {
    int t = L - 7168;
    int cx = t & 31, ry = t >> 5;
    tr_body(outw, outwT, 1024, 1024, cx * 32, ry * 32, (bf16(*)[33])pm, tid);
  } else {
    // rpe cumsum (scaled by LOG2E) into padded row
    float* ssum = (float*)pm;
    int n = L - 8192;
    float* crow = cum + (size_t)n * CUMROW;
    if (tid < CUMPAD) crow[tid] = 0.f;          // zero the pad
    float loc[8];
    float s = 0.f;
    int base = tid * 8;
#pragma unroll
    for (int u = 0; u < 8; ++u) {
      loc[u] = rpe[n * S_ + base + u];
      s += loc[u];
    }
    ssum[tid] = s;
    __syncthreads();
    float own = s;
    for (int off = 1; off < 256; off <<= 1) {
      float v = (tid >= off) ? ssum[tid - off] : 0.f;
      __syncthreads();
      ssum[tid] += v;
      __syncthreads();
    }
    float run = ssum[tid] - own;   // exclusive prefix of this thread's chunk
#pragma unroll
    for (int u = 0; u < 8; ++u) {
      run += loc[u];
      crow[CUMPAD + base + u] = run * LOG2E;
    }
  }
}

// ---------------------------------------------------------------------------
// GEMM — unchanged from R8.
// ---------------------------------------------------------------------------
template <int MODE>
__global__ __launch_bounds__(256, MODE == 0 ? 3 : 2)
void gemm_bt(const bf16* __restrict__ A, const bf16* __restrict__ Bt,
             bf16* __restrict__ C0, bf16* __restrict__ C1, bf16* __restrict__ C2,
             float* __restrict__ F0) {
  constexpr int NT = (MODE == 0) ? 4 : 2;     // n-subtiles per wave
  constexpr int NB = NT * 32;                 // block n-extent: 128 or 64
  constexpr int BUFSZ = 8192 + NB * 64;       // A 8KB + B NB*32*2B
  __shared__ char smem[MODE == 0 ? 36864 : 24576] __attribute__((aligned(16)));
  const int tid = threadIdx.x, lane = tid & 63, w = tid >> 6;
  const int lr = lane & 15, lq = lane >> 4;
  const int m0 = blockIdx.y * 128, n0 = blockIdx.x * NB;
  const int wm = (w & 1) * 64, wn = (w >> 1) * (NT * 16);

  f32x4 acc[4][NT] = {};

  auto stage = [&](int buf, int k0) {
    char* dst = smem + buf * BUFSZ;
#pragma unroll
    for (int t = 0; t < 2; ++t) {
      int c = t * 256 + tid;
      int row = c >> 2, ch = c & 3;
      int k8 = (ch ^ ((row >> 1) & 3)) * 8;
      async16(A + (size_t)(m0 + row) * 1024 + k0 + k8, dst + c * 16);
    }
#pragma unroll
    for (int t = 0; t < NB / 64; ++t) {
      int c = t * 256 + tid;
      int row = c >> 2, ch = c & 3;
      int k8 = (ch ^ ((row >> 1) & 3)) * 8;
      async16(Bt + (size_t)(n0 + row) * 1024 + k0 + k8, dst + 8192 + c * 16);
    }
  };

  stage(0, 0);

  for (int s = 0; s < 32; ++s) {
    const int bsel = s & 1;
    __syncthreads();
    if (s + 1 < 32) stage(bsel ^ 1, (s + 1) * 32);

    const bf16* As = (const bf16*)(smem + bsel * BUFSZ);
    const bf16* Bs = (const bf16*)(smem + bsel * BUFSZ + 8192);
    bf16x8 af[4], bfr[NT];
#pragma unroll
    for (int mt = 0; mt < 4; ++mt) {
      int row = wm + mt * 16 + lr;
      af[mt] = *(const bf16x8*)(As + row * 32 + ((lq ^ ((row >> 1) & 3)) << 3));
    }
#pragma unroll
    for (int nt = 0; nt < NT; ++nt) {
      int row = wn + nt * 16 + lr;
      bfr[nt] = *(const bf16x8*)(Bs + row * 32 + ((lq ^ ((row >> 1) & 3)) << 3));
    }
#pragma unroll
    for (int mt = 0; mt < 4; ++mt)
#pragma unroll
      for (int nt = 0; nt < NT; ++nt)
        acc[mt][nt] = MFMA16(af[mt], bfr[nt], acc[mt][nt]);
  }

  if (MODE == 0) {
    __syncthreads();   // all As/Bs reads done; reuse LDS for epilogue tiles
    bf16* E = (bf16*)smem + w * (64 * 72);   // wave-private [64][72]
    const int cbase = n0 + wn;               // 64-aligned
    const int mm = cbase >> 10, nn = (cbase >> 6) & 15;
    const int bb = (m0 + wm) >> 11;
    const int sbase = (m0 + wm) & 2047;
    if (mm < 2) {
#pragma unroll
      for (int mt = 0; mt < 4; ++mt)
#pragma unroll
        for (int nt = 0; nt < 4; ++nt)
#pragma unroll
          for (int r = 0; r < 4; ++r)
            E[(mt * 16 + lq * 4 + r) * 72 + nt * 16 + lr] =
                __float2bfloat16(acc[mt][nt][r]);
      bf16* dst = (mm == 0 ? C0 : C1) +
                  ((size_t)(bb * NH + nn) * S_ + sbase) * DH;
#pragma unroll
      for (int it = 0; it < 8; ++it) {
        int c = it * 64 + lane;
        int rw = c >> 3, c8 = c & 7;
        *(uint4*)(dst + (size_t)rw * DH + c8 * 8) =
            *(const uint4*)(E + rw * 72 + c8 * 8);
      }
    } else {
#pragma unroll
      for (int mt = 0; mt < 4; ++mt)
#pragma unroll
        for (int nt = 0; nt < 4; ++nt)
#pragma unroll
          for (int r = 0; r < 4; ++r)
            E[(nt * 16 + lr) * 72 + mt * 16 + lq * 4 + r] =
                __float2bfloat16(acc[mt][nt][r]);
      bf16* dst = C2 + (size_t)(bb * NH + nn) * DH * S_;
#pragma unroll
      for (int it = 0; it < 8; ++it) {
        int c = it * 64 + lane;
        int dr = c >> 3, c8 = c & 7;
        *(uint4*)(dst + (size_t)dr * S_ + sbase + c8 * 8) =
            *(const uint4*)(E + dr * 72 + c8 * 8);
      }
    }
  } else {
#pragma unroll
    for (int mt = 0; mt < 4; ++mt)
#pragma unroll
      for (int nt = 0; nt < NT; ++nt)
#pragma unroll
        for (int r = 0; r < 4; ++r) {
          int rM = m0 + wm + mt * 16 + lq * 4 + r;
          int cN = n0 + wn + nt * 16 + lr;
          F0[(size_t)rM * 1024 + cN] = acc[mt][nt][r];
        }
  }
}

// ---------------------------------------------------------------------------
// Flash attention, R10: R9 structure with the VMCNT ORDERING FIX.
// R9 regression mechanism: per unit, prefetch global_load_lds issued BEFORE
// the bias global loads -> s_waitcnt for the bias quads (oldest-first vmcnt
// semantics) drained the whole next-tile prefetch (~845 cyc/unit measured:
// 3630 -> 4475 cyc/unit-slot). Fix: hoist consumer-side global loads so
// they are OLDER than the prefetch: barrier -> (tile-start) Q loads ->
// bias cv loads -> stage prefetch -> QK (waits qf only) -> softmax (waits
// cv only, vmcnt<=8 leaves stage in flight) -> PV -> barrier.
// Keeps R9's wins: 4-way j-split (8 b128 LDS reads/wave/unit), conflicts=0,
// cum LDS staging gone (bias direct from padded global row, L1-resident).
// LDS: K/V dbuf [0,65536); combL [3][64] f32 [65536,66304).
// ---------------------------------------------------------------------------
__device__ __forceinline__ void fa_stage(const bf16* __restrict__ k,
                                         const bf16* __restrict__ vt,
                                         char* smem, int bn, int jb,
                                         int buf, int tid) {
  char* dst = smem + buf * 32768;
  // K tile: rows jb..jb+127 (128B each, 8 chunks); slot (row,ch) holds
  // global chunk ch^kk(row), kk = (row&3)|((row>>1)&4). 1024 chunks.
  const char* ksrc = (const char*)(k + ((size_t)bn * S_ + jb) * DH);
#pragma unroll
  for (int t = 0; t < 4; ++t) {
    int c = t * 256 + tid;
    int row = c >> 3, ch = c & 7;
    int cs = ch ^ ((row & 3) | ((row >> 1) & 4));
    async16(ksrc + row * 128 + cs * 16, dst + c * 16);
  }
  // Vt tile: d rows 0..63, cols jb..jb+127 (256B, 16 chunks); slot (d,ch)
  // holds global chunk ch^(d&15). 1024 chunks.
  const char* vsrc = (const char*)(vt + (size_t)bn * DH * S_);
#pragma unroll
  for (int t = 0; t < 4; ++t) {
    int c = t * 256 + tid;
    int row = c >> 4, ch = c & 15;            // row = d index
    int cs = ch ^ (row & 15);
    async16(vsrc + (size_t)row * (S_ * 2) + jb * 2 + cs * 16,
            dst + 16384 + c * 16);
  }
}

__global__ __launch_bounds__(256, 2)
void fa_kernel(const bf16* __restrict__ q, const bf16* __restrict__ k,
               const bf16* __restrict__ vt, const float* __restrict__ cum,
               bf16* __restrict__ mix) {
  __shared__ char smem[66304] __attribute__((aligned(16)));
  float* combL = (float*)(smem + 65536);        // [3][64]

  const int tid = threadIdx.x, lane = tid & 63, w = tid >> 6;  // w = jh: 0..3
  const int lr = lane & 15, lq = lane >> 4;
  const int jh = w;                             // j-quarter (32 cols)

  const int L = blockIdx.x;                     // 0..511
  const int xcd = L & 7, slot = L >> 3;         // slot 0..63
  const int bn = xcd + 8 * (slot & 3);          // 4 heads per XCD
  const int pp = slot >> 2;                     // pair index 0..15
  const int n = bn & (NH - 1);
  const int b = bn >> 4;
  const float* cumnP = cum + (size_t)n * CUMROW + CUMPAD;

  const int T0 = 31 - pp;                       // heavy tile
  const int T1 = pp;                            // light tile
  const int nu0 = (T0 + 2) >> 1;                // units in tile 0

  // all-ones B fragment for the l row-sum MFMA
  bf16x8 ones;
#pragma unroll
  for (int u = 0; u < 8; ++u) ones[u] = (short)0x3F80;
  const f32x4 fz = {0.f, 0.f, 0.f, 0.f};

  // permuted-K swizzle key (independent of kd/nt2/jh)
  const int kkey = (lr & 3) | (((lr >> 2) & 1) << 2);

  bf16x8 qf[4][2];                              // [is][kd]
  f32x4 oacc[4][4];                             // [is][dt]
  f32x4 lacc[4];

  // prologue: stage unit 0 (tile T0, jt 0) into buf 0
  fa_stage(k, vt, smem, bn, 0, 0, tid);

  int jt = 0, i0 = T0 * 64, nu = nu0;

  for (int g = 0; g < 17; ++g) {
    const int bsel = g & 1;
    const char* kb = smem + bsel * 32768;
    const char* vb = kb + 16384;
    const int jb = jt * 128;
    const bool diag = (jt == nu - 1);           // last unit of this tile
    const int doff = i0 - jb;                   // diag: 0 or 64; else >=128

    __syncthreads();   // staged data for g visible; buf^1 prior reads done

    // --- consumer-side global loads FIRST (older than prefetch in the
    // vmem queue, so waiting on them never drains the prefetch) ---
    if (jt == 0) {
      // new tile: load Q fragments (B-operand for S^T = K*Q^T), reset acc
      const bf16* qbase = q + ((size_t)bn * S_ + i0) * DH;
#pragma unroll
      for (int is = 0; is < 4; ++is) {
#pragma unroll
        for (int kd = 0; kd < 2; ++kd)
          qf[is][kd] = *(const bf16x8*)(qbase + (is * 16 + lr) * DH + kd * 32 + lq * 8);
        lacc[is] = fz;
#pragma unroll
        for (int dt = 0; dt < 4; ++dt) oacc[is][dt] = fz;
      }
    }
    // bias quads for THIS unit: cv[is][nt2][m] = cum[gidx+m] (padded row)
    f32x4 cv[4][2];
#pragma unroll
    for (int is = 0; is < 4; ++is)
#pragma unroll
      for (int nt2 = 0; nt2 < 2; ++nt2) {
        int jl = jh * 32 + lq * 8 + nt2 * 4;
        int gidx = doff + (is * 16 + lr) - jl - 3;
        cv[is][nt2] = *(const f32x4u*)(cumnP + gidx);
      }

    // --- prefetch unit g+1 into the other buffer (flies under compute) ---
    if (g + 1 < 17) {
      int gn = g + 1, jtn;
      if (gn < nu0) jtn = gn;
      else          jtn = gn - nu0;
      fa_stage(k, vt, smem, bn, jtn * 128, bsel ^ 1, tid);
    }

    // S^T = K * Q^T with PERMUTED K rows over this wave's 32-col chunk.
    // A-row lr of MFMA nt2 loads krow = jh*32 + (lr>>2)*8 + nt2*4 + (lr&3),
    // so C position (lq*4+r) holds j = jh*32 + lq*8 + nt2*4 + r — the PV
    // A-fragment layout. kf shared across 4 i-subtiles.
    f32x4 sa[4][2] = {};
#pragma unroll
    for (int kd = 0; kd < 2; ++kd)
#pragma unroll
      for (int nt2 = 0; nt2 < 2; ++nt2) {
        int krow = jh * 32 + ((lr >> 2) << 3) + nt2 * 4 + (lr & 3);
        bf16x8 kf = *(const bf16x8*)(kb + krow * 128 +
                        (((kd * 4 + lq) ^ kkey) << 4));
#pragma unroll
        for (int is = 0; is < 4; ++is)
          sa[is][nt2] = MFMA16(kf, qf[is][kd], sa[is][nt2]);
      }

    // p = exp2(s*SCALE2 + cum[i-j]) straight into PV A-fragments.
    // bias(r) = cv[3-r].
    bf16x8 pf[4];
#pragma unroll
    for (int is = 0; is < 4; ++is) {
      const int ilocI = is * 16 + lr;           // 0..63
#pragma unroll
      for (int nt2 = 0; nt2 < 2; ++nt2) {
        int jl = jh * 32 + lq * 8 + nt2 * 4;
        if (!diag) {
#pragma unroll
          for (int r = 0; r < 4; ++r)
            pf[is][nt2 * 4 + r] =
                bf16bits(exp2f(sa[is][nt2][r] * SCALE2 + cv[is][nt2][3 - r]));
        } else {
#pragma unroll
          for (int r = 0; r < 4; ++r) {
            float pv = (doff + ilocI - jl - r >= 0)
                           ? exp2f(sa[is][nt2][r] * SCALE2 + cv[is][nt2][3 - r])
                           : 0.f;
            pf[is][nt2 * 4 + r] = bf16bits(pv);
          }
        }
      }
    }

    // O += P V; l += P 1 — pf straight from registers; vf shared across is.
#pragma unroll
    for (int is = 0; is < 4; ++is)
      lacc[is] = MFMA16(pf[is], ones, lacc[is]);
#pragma unroll
    for (int dt = 0; dt < 4; ++dt) {
      int vrow = dt * 16 + lr;
      bf16x8 vf = *(const bf16x8*)(vb + vrow * 256 +
                      (((jh * 4 + lq) ^ (vrow & 15)) << 4));
#pragma unroll
      for (int is = 0; is < 4; ++is)
        oacc[is][dt] = MFMA16(pf[is], vf, oacc[is][dt]);
    }

    if (diag) {
      // tile end: combine the 4 j-quarters (additive — no-max exp2 softmax).
      // 2-stage pairwise tree through the consumed K/V buffer (32KB free).
      __syncthreads();   // all reads of buf bsel complete
      f32x4* scrq = (f32x4*)(smem + bsel * 32768);   // 2048 f32x4
      if (jh == 1 || jh == 3) {
        f32x4* dst = scrq + (jh == 1 ? 0 : 1024);
#pragma unroll
        for (int is = 0; is < 4; ++is)
#pragma unroll
          for (int dt = 0; dt < 4; ++dt)
            dst[(is * 4 + dt) * 64 + lane] = oacc[is][dt];
      }
      if (jh >= 1 && lr == 0) {
#pragma unroll
        for (int is = 0; is < 4; ++is)
#pragma unroll
          for (int r = 0; r < 4; ++r)
            combL[(jh - 1) * 64 + is * 16 + lq * 4 + r] = lacc[is][r];
      }
      __syncthreads();
      if (jh == 0) {
#pragma unroll
        for (int is = 0; is < 4; ++is)
#pragma unroll
          for (int dt = 0; dt < 4; ++dt)
            oacc[is][dt] += scrq[(is * 4 + dt) * 64 + lane];
      } else if (jh == 2) {
#pragma unroll
        for (int is = 0; is < 4; ++is)
#pragma unroll
          for (int dt = 0; dt < 4; ++dt)
            oacc[is][dt] += scrq[1024 + (is * 4 + dt) * 64 + lane];
      }
      __syncthreads();
      if (jh == 2) {
#pragma unroll
        for (int is = 0; is < 4; ++is)
#pragma unroll
          for (int dt = 0; dt < 4; ++dt)
            scrq[(is * 4 + dt) * 64 + lane] = oacc[is][dt];
      }
      __syncthreads();
      if (jh == 0) {
#pragma unroll
        for (int is = 0; is < 4; ++is) {
#pragma unroll
          for (int dt = 0; dt < 4; ++dt)
            oacc[is][dt] += scrq[(is * 4 + dt) * 64 + lane];
#pragma unroll
          for (int r = 0; r < 4; ++r)
            lacc[is][r] += combL[is * 16 + lq * 4 + r] +
                           combL[64 + is * 16 + lq * 4 + r] +
                           combL[128 + is * 16 + lq * 4 + r];
        }
        // store mix[b][s][n][d] for all 64 tile rows
#pragma unroll
        for (int is = 0; is < 4; ++is)
#pragma unroll
          for (int dt = 0; dt < 4; ++dt)
#pragma unroll
            for (int r = 0; r < 4; ++r) {
              int i = i0 + is * 16 + lq * 4 + r;
              int d = dt * 16 + lr;
              mix[((size_t)(b * S_ + i) * NH + n) * DH + d] =
                  __float2bfloat16(oacc[is][dt][r] / lacc[is][r]);
            }
      }
      jt = 0; i0 = T1 * 64; nu = (T1 + 2) >> 1;  // switch to light tile
    } else {
      ++jt;
    }
  }
}

// ---------------------------------------------------------------------------
extern "C" void kernel_launch(void* const* d_in, const int* in_sizes, int n_in,
                              void* d_out, int out_size, void* d_ws, size_t ws_size,
                              hipStream_t stream) {
  const float* x     = (const float*)d_in[0];   // [B,S,H] f32
  const float* qkv   = (const float*)d_in[1];   // [H,3,N,D] f32 == [1024][3072]
  const float* out_w = (const float*)d_in[2];   // [N,D,H] f32   == [1024][1024]
  const float* rpe   = (const float*)d_in[3];   // [N,S] f32
  float* out = (float*)d_out;                   // [B,S,H] f32

  char* ws = (char*)d_ws;
  bf16* qkvT  = (bf16*)(ws + 0);          // [3072][1024] bf16   6291456 B
  bf16* outwT = (bf16*)(ws + 6291456);    // [1024][1024] bf16   2097152 B
  bf16* xb    = (bf16*)(ws + 8388608);    // [4096][1024] bf16   8388608 B
  bf16* qb    = (bf16*)(ws + 16777216);   // [bn][S][D]          8388608 B
  bf16* kb    = (bf16*)(ws + 25165824);   // [bn][S][D]          8388608 B
  bf16* vtb   = (bf16*)(ws + 33554432);   // [bn][D][S]          8388608 B
  bf16* mixb  = (bf16*)(ws + 41943040);   // [b][s][n][d]        8388608 B
  float* cum  = (float*)(ws + 50331648);  // [N][CUMROW] f32      139520 B

  // 1. fused prep: convert x, transpose+convert weights, padded rpe cumsum
  prep<<<8208, 256, 0, stream>>>(x, xb, qkv, qkvT, out_w, outwT, rpe, cum);
  // 2. QKV projection (V written pre-transposed; 768 blocks = 3/CU)
  gemm_bt<0><<<dim3(3072 / 128, 4096 / 128), 256, 0, stream>>>(xb, qkvT, qb, kb, vtb, nullptr);
  // 3. attention: 512 blocks, 17 64x128-units each (pair {31-p, p}),
  //    4-way j-split, in-reg P, hoisted bias loads (vmcnt-order fix)
  fa_kernel<<<512, 256, 0, stream>>>(qb, kb, vtb, cum, mixb);
  // 4. output projection (f32 out; 128x64 tiles -> 512 blocks = 2/CU)
  gemm_bt<1><<<dim3(1024 / 64, 4096 / 128), 256, 0, stream>>>(mixb, outwT, nullptr, nullptr, nullptr, out);
}

// Round 11
// 182.456 us; speedup vs baseline: 1.0371x; 1.0082x over previous
//
#include <hip/hip_runtime.h>
#include <hip/hip_bf16.h>
#include <cstdint>
#include <cstddef>

// Problem constants
#define B_   2
#define S_   2048
#define H_   1024
#define NH   16
#define DH   64
#define LOG2E 1.4426950408889634f
#define SCALE2 (0.125f * LOG2E)   // D^-0.5 * log2(e): softmax done in exp2 domain
#define CUMPAD 132                // zero-pad floats before cum row (kept from R9)
#define CUMROW (CUMPAD + S_)      // 2180 floats per head row

typedef __hip_bfloat16 bf16;
typedef short bf16x8 __attribute__((ext_vector_type(8)));   // 8 bf16 in 4 VGPRs
typedef float f32x4 __attribute__((ext_vector_type(4)));

#define MFMA16(a, b, c) __builtin_amdgcn_mfma_f32_16x16x32_bf16((a), (b), (c), 0, 0, 0)

__device__ __forceinline__ void async16(const void* g, void* l) {
  __builtin_amdgcn_global_load_lds(
      (const __attribute__((address_space(1))) void*)g,
      (__attribute__((address_space(3))) void*)l,
      16, 0, 0);
}
__device__ __forceinline__ void async4(const void* g, void* l) {
  __builtin_amdgcn_global_load_lds(
      (const __attribute__((address_space(1))) void*)g,
      (__attribute__((address_space(3))) void*)l,
      4, 0, 0);
}

__device__ __forceinline__ short bf16bits(float v) {
  bf16 t = __float2bfloat16(v);
  return *reinterpret_cast<short*>(&t);
}

// ---------------------------------------------------------------------------
// Fused prep kernel (one dispatch, grid 8208) — unchanged from R10.
// ---------------------------------------------------------------------------
__device__ __forceinline__ void tr_body(const float* __restrict__ src,
                                        bf16* __restrict__ dst, int R, int C,
                                        int c0, int r0, bf16 (*tile)[33], int tid) {
  int tx = tid & 31, ty = tid >> 5;   // 32 x 8
  for (int i = 0; i < 32; i += 8)
    tile[ty + i][tx] = __float2bfloat16(src[(size_t)(r0 + ty + i) * C + c0 + tx]);
  __syncthreads();
  for (int i = 0; i < 32; i += 8)
    dst[(size_t)(c0 + ty + i) * R + r0 + tx] = tile[tx][ty + i];
}

__global__ __launch_bounds__(256)
void prep(const float* __restrict__ x, bf16* __restrict__ xb,
          const float* __restrict__ qkv, bf16* __restrict__ qkvT,
          const float* __restrict__ outw, bf16* __restrict__ outwT,
          const float* __restrict__ rpe, float* __restrict__ cum) {
  __shared__ char pm[2176] __attribute__((aligned(16)));
  const int L = blockIdx.x, tid = threadIdx.x;
  if (L < 4096) {
    int i = (L * 256 + tid) * 4;
    float4 v = *(const float4*)(x + i);
    bf16 o[4] = {__float2bfloat16(v.x), __float2bfloat16(v.y),
                 __float2bfloat16(v.z), __float2bfloat16(v.w)};
    *(uint64_t*)(xb + i) = *(const uint64_t*)o;
  } else if (L < 7168) {
    int t = L - 4096;
    int cx = t % 96, ry = t / 96;
    tr_body(qkv, qkvT, 1024, 3072, cx * 32, ry * 32, (bf16(*)[33])pm, tid);
  } else if (L < 8192) {
    int t = L - 7168;
    int cx = t & 31, ry = t >> 5;
    tr_body(outw, outwT, 1024, 1024, cx * 32, ry * 32, (bf16(*)[33])pm, tid);
  } else {
    // rpe cumsum (scaled by LOG2E) into padded row
    float* ssum = (float*)pm;
    int n = L - 8192;
    float* crow = cum + (size_t)n * CUMROW;
    if (tid < CUMPAD) crow[tid] = 0.f;          // zero the pad
    float loc[8];
    float s = 0.f;
    int base = tid * 8;
#pragma unroll
    for (int u = 0; u < 8; ++u) {
      loc[u] = rpe[n * S_ + base + u];
      s += loc[u];
    }
    ssum[tid] = s;
    __syncthreads();
    float own = s;
    for (int off = 1; off < 256; off <<= 1) {
      float v = (tid >= off) ? ssum[tid - off] : 0.f;
      __syncthreads();
      ssum[tid] += v;
      __syncthreads();
    }
    float run = ssum[tid] - own;   // exclusive prefix of this thread's chunk
#pragma unroll
    for (int u = 0; u < 8; ++u) {
      run += loc[u];
      crow[CUMPAD + base + u] = run * LOG2E;
    }
  }
}

// ---------------------------------------------------------------------------
// GEMM — unchanged from R8/R10.
// ---------------------------------------------------------------------------
template <int MODE>
__global__ __launch_bounds__(256, MODE == 0 ? 3 : 2)
void gemm_bt(const bf16* __restrict__ A, const bf16* __restrict__ Bt,
             bf16* __restrict__ C0, bf16* __restrict__ C1, bf16* __restrict__ C2,
             float* __restrict__ F0) {
  constexpr int NT = (MODE == 0) ? 4 : 2;     // n-subtiles per wave
  constexpr int NB = NT * 32;                 // block n-extent: 128 or 64
  constexpr int BUFSZ = 8192 + NB * 64;       // A 8KB + B NB*32*2B
  __shared__ char smem[MODE == 0 ? 36864 : 24576] __attribute__((aligned(16)));
  const int tid = threadIdx.x, lane = tid & 63, w = tid >> 6;
  const int lr = lane & 15, lq = lane >> 4;
  const int m0 = blockIdx.y * 128, n0 = blockIdx.x * NB;
  const int wm = (w & 1) * 64, wn = (w >> 1) * (NT * 16);

  f32x4 acc[4][NT] = {};

  auto stage = [&](int buf, int k0) {
    char* dst = smem + buf * BUFSZ;
#pragma unroll
    for (int t = 0; t < 2; ++t) {
      int c = t * 256 + tid;
      int row = c >> 2, ch = c & 3;
      int k8 = (ch ^ ((row >> 1) & 3)) * 8;
      async16(A + (size_t)(m0 + row) * 1024 + k0 + k8, dst + c * 16);
    }
#pragma unroll
    for (int t = 0; t < NB / 64; ++t) {
      int c = t * 256 + tid;
      int row = c >> 2, ch = c & 3;
      int k8 = (ch ^ ((row >> 1) & 3)) * 8;
      async16(Bt + (size_t)(n0 + row) * 1024 + k0 + k8, dst + 8192 + c * 16);
    }
  };

  stage(0, 0);

  for (int s = 0; s < 32; ++s) {
    const int bsel = s & 1;
    __syncthreads();
    if (s + 1 < 32) stage(bsel ^ 1, (s + 1) * 32);

    const bf16* As = (const bf16*)(smem + bsel * BUFSZ);
    const bf16* Bs = (const bf16*)(smem + bsel * BUFSZ + 8192);
    bf16x8 af[4], bfr[NT];
#pragma unroll
    for (int mt = 0; mt < 4; ++mt) {
      int row = wm + mt * 16 + lr;
      af[mt] = *(const bf16x8*)(As + row * 32 + ((lq ^ ((row >> 1) & 3)) << 3));
    }
#pragma unroll
    for (int nt = 0; nt < NT; ++nt) {
      int row = wn + nt * 16 + lr;
      bfr[nt] = *(const bf16x8*)(Bs + row * 32 + ((lq ^ ((row >> 1) & 3)) << 3));
    }
#pragma unroll
    for (int mt = 0; mt < 4; ++mt)
#pragma unroll
      for (int nt = 0; nt < NT; ++nt)
        acc[mt][nt] = MFMA16(af[mt], bfr[nt], acc[mt][nt]);
  }

  if (MODE == 0) {
    __syncthreads();   // all As/Bs reads done; reuse LDS for epilogue tiles
    bf16* E = (bf16*)smem + w * (64 * 72);   // wave-private [64][72]
    const int cbase = n0 + wn;               // 64-aligned
    const int mm = cbase >> 10, nn = (cbase >> 6) & 15;
    const int bb = (m0 + wm) >> 11;
    const int sbase = (m0 + wm) & 2047;
    if (mm < 2) {
#pragma unroll
      for (int mt = 0; mt < 4; ++mt)
#pragma unroll
        for (int nt = 0; nt < 4; ++nt)
#pragma unroll
          for (int r = 0; r < 4; ++r)
            E[(mt * 16 + lq * 4 + r) * 72 + nt * 16 + lr] =
                __float2bfloat16(acc[mt][nt][r]);
      bf16* dst = (mm == 0 ? C0 : C1) +
                  ((size_t)(bb * NH + nn) * S_ + sbase) * DH;
#pragma unroll
      for (int it = 0; it < 8; ++it) {
        int c = it * 64 + lane;
        int rw = c >> 3, c8 = c & 7;
        *(uint4*)(dst + (size_t)rw * DH + c8 * 8) =
            *(const uint4*)(E + rw * 72 + c8 * 8);
      }
    } else {
#pragma unroll
      for (int mt = 0; mt < 4; ++mt)
#pragma unroll
        for (int nt = 0; nt < 4; ++nt)
#pragma unroll
          for (int r = 0; r < 4; ++r)
            E[(nt * 16 + lr) * 72 + mt * 16 + lq * 4 + r] =
                __float2bfloat16(acc[mt][nt][r]);
      bf16* dst = C2 + (size_t)(bb * NH + nn) * DH * S_;
#pragma unroll
      for (int it = 0; it < 8; ++it) {
        int c = it * 64 + lane;
        int dr = c >> 3, c8 = c & 7;
        *(uint4*)(dst + (size_t)dr * S_ + sbase + c8 * 8) =
            *(const uint4*)(E + dr * 72 + c8 * 8);
      }
    }
  } else {
#pragma unroll
    for (int mt = 0; mt < 4; ++mt)
#pragma unroll
      for (int nt = 0; nt < NT; ++nt)
#pragma unroll
        for (int r = 0; r < 4; ++r) {
          int rM = m0 + wm + mt * 16 + lq * 4 + r;
          int cN = n0 + wn + nt * 16 + lr;
          F0[(size_t)rM * 1024 + cN] = acc[mt][nt][r];
        }
  }
}

// ---------------------------------------------------------------------------
// Flash attention, R11: 16 WAVES/CU. R7-R10 showed fa is latency-bound
// (no pipe >46% busy; every instr-shaving change <=10%) at 8 waves/CU.
// Restructure: 512-thread blocks (8 waves = 2 rg x 4 jh; wave = 32 Q-rows
// x 32 j-cols of a 64-row x 128-col unit), grid 512 = 2 equal-duration
// blocks/CU = 16 waves/CU. Retained proven pieces: pair {31-p,p} = 17
// units; in-reg P via permuted K rows (kkey/krow from R9/R10, conflicts=0);
// dbuf + prefetch-after-barrier; bias via R7's LDS-staged 4-phase windows
// (stride 200 == 8 mod 32 banks; R10 proved global quads worse).
// j-combine: R10's pairwise tree per rg through the consumed K/V buffer.
// q,k: [bn][S][D] bf16;  vt: [bn][D][S] bf16;  cum: [N][CUMROW] f32 padded;
// mix out: [b][s][n][d] bf16
// LDS: K/V dbuf [0,65536) (buf b at b*32768: K 16K, V 16K);
//      cum [2][4][200] f32 [65536,71936); combL [2][3][32] f32
//      [71936,72704). 72704 x 2 blocks/CU = 145.4 KB <= 160 KB.
// ---------------------------------------------------------------------------
__device__ __forceinline__ void fa_stage(const bf16* __restrict__ k,
                                         const bf16* __restrict__ vt,
                                         const float* __restrict__ cumn,
                                         char* smem, int bn, int i0, int jb,
                                         int buf, int tid) {
  char* dst = smem + buf * 32768;
  // K tile: rows jb..jb+127 (128B each, 8 chunks); slot (row,ch) holds
  // global chunk ch^kk(row), kk = (row&3)|((row>>1)&4). 1024 chunks.
  const char* ksrc = (const char*)(k + ((size_t)bn * S_ + jb) * DH);
#pragma unroll
  for (int t = 0; t < 2; ++t) {
    int c = t * 512 + tid;
    int row = c >> 3, ch = c & 7;
    int cs = ch ^ ((row & 3) | ((row >> 1) & 4));
    async16(ksrc + row * 128 + cs * 16, dst + c * 16);
  }
  // Vt tile: d rows 0..63, cols jb..jb+127 (256B, 16 chunks); slot (d,ch)
  // holds global chunk ch^(d&15). 1024 chunks.
  const char* vsrc = (const char*)(vt + (size_t)bn * DH * S_);
#pragma unroll
  for (int t = 0; t < 2; ++t) {
    int c = t * 512 + tid;
    int row = c >> 4, ch = c & 15;            // row = d index
    int cs = ch ^ (row & 15);
    async16(vsrc + (size_t)row * (S_ * 2) + jb * 2 + cs * 16,
            dst + 16384 + c * 16);
  }
  // cum windows: win[t] = cumn[clamp(i0-jb-127+t)], t<194; 4 phases,
  // stride 200 words (== 8 mod 32 banks). (R7-proven mechanism.)
  if (tid < 194) {
    float* cdst = (float*)(smem + 65536) + buf * 800;  // 4*200
    int base = i0 - jb - 127 + tid;
#pragma unroll
    for (int p = 0; p < 4; ++p) {
      int src = base + p;
      src = src < 0 ? 0 : (src > S_ - 1 ? S_ - 1 : src);
      async4(cumn + src, cdst + p * 200 + tid);
    }
  }
}

__global__ __launch_bounds__(512, 4)
void fa_kernel(const bf16* __restrict__ q, const bf16* __restrict__ k,
               const bf16* __restrict__ vt, const float* __restrict__ cum,
               bf16* __restrict__ mix) {
  __shared__ char smem[72704] __attribute__((aligned(16)));
  float* combL = (float*)(smem + 71936);        // [2 rg][3][32]

  const int tid = threadIdx.x, lane = tid & 63, w = tid >> 6;  // w: 0..7
  const int lr = lane & 15, lq = lane >> 4;
  const int jh = w & 3, rg = w >> 2;            // j-quarter (32 cols), row-grp

  const int L = blockIdx.x;                     // 0..511
  const int xcd = L & 7, slot = L >> 3;         // slot 0..63
  const int bn = xcd + 8 * (slot & 3);          // 4 heads per XCD
  const int pp = slot >> 2;                     // pair index 0..15
  const int n = bn & (NH - 1);
  const int b = bn >> 4;
  const float* cumn = cum + (size_t)n * CUMROW + CUMPAD;

  const int T0 = 31 - pp;                       // heavy tile
  const int T1 = pp;                            // light tile
  const int nu0 = (T0 + 2) >> 1;                // units in tile 0

  // all-ones B fragment for the l row-sum MFMA
  bf16x8 ones;
#pragma unroll
  for (int u = 0; u < 8; ++u) ones[u] = (short)0x3F80;
  const f32x4 fz = {0.f, 0.f, 0.f, 0.f};

  // permuted-K swizzle key (independent of kd/nt2/jh)
  const int kkey = (lr & 3) | (((lr >> 2) & 1) << 2);

  bf16x8 qf[2][2];                              // [is][kd]
  f32x4 oacc[2][4];                             // [is][dt]
  f32x4 lacc[2];

  // prologue: stage unit 0 (tile T0, jt 0) into buf 0
  fa_stage(k, vt, cumn, smem, bn, T0 * 64, 0, 0, tid);

  int jt = 0, i0 = T0 * 64, nu = nu0;

  for (int g = 0; g < 17; ++g) {
    const int bsel = g & 1;
    const char* kb = smem + bsel * 32768;
    const char* vb = kb + 16384;
    const float* cumB = (const float*)(smem + 65536) + bsel * 800;
    const int jb = jt * 128;
    const bool diag = (jt == nu - 1);           // last unit of this tile
    const int doff = i0 - jb;                   // diag: 0 or 64; else >=128

    __syncthreads();   // staged data for g visible; buf^1 prior reads done

    // prefetch unit g+1 into the other buffer (flies during this compute)
    if (g + 1 < 17) {
      int gn = g + 1, tin, jtn;
      if (gn < nu0) { tin = T0; jtn = gn; }
      else          { tin = T1; jtn = gn - nu0; }
      fa_stage(k, vt, cumn, smem, bn, tin * 64, jtn * 128, bsel ^ 1, tid);
    }

    if (jt == 0) {
      // new tile: load Q fragments (B-operand for S^T = K*Q^T), reset acc
      const bf16* qbase = q + ((size_t)bn * S_ + i0 + rg * 32) * DH;
#pragma unroll
      for (int is = 0; is < 2; ++is) {
#pragma unroll
        for (int kd = 0; kd < 2; ++kd)
          qf[is][kd] = *(const bf16x8*)(qbase + (is * 16 + lr) * DH + kd * 32 + lq * 8);
        lacc[is] = fz;
#pragma unroll
        for (int dt = 0; dt < 4; ++dt) oacc[is][dt] = fz;
      }
    }

    // S^T = K * Q^T with PERMUTED K rows over this wave's 32-col chunk.
    // A-row lr of MFMA nt2 loads krow = jh*32 + (lr>>2)*8 + nt2*4 + (lr&3),
    // so C position (lq*4+r) holds j = jh*32 + lq*8 + nt2*4 + r — the PV
    // A-fragment layout. kf shared across the 2 i-subtiles.
    f32x4 sa[2][2] = {};
#pragma unroll
    for (int kd = 0; kd < 2; ++kd)
#pragma unroll
      for (int nt2 = 0; nt2 < 2; ++nt2) {
        int krow = jh * 32 + ((lr >> 2) << 3) + nt2 * 4 + (lr & 3);
        bf16x8 kf = *(const bf16x8*)(kb + krow * 128 +
                        (((kd * 4 + lq) ^ kkey) << 4));
        sa[0][nt2] = MFMA16(kf, qf[0][kd], sa[0][nt2]);
        sa[1][nt2] = MFMA16(kf, qf[1][kd], sa[1][nt2]);
      }

    // p = exp2(s*SCALE2 + cum[i-j]) straight into PV A-fragments.
    // One b128 bias read per reg-quad from the staged window:
    // Xm3 = 124 + ilocI - jl in [0,187]; cv[m] = win[Xm3+m]; bias(r)=cv[3-r].
    bf16x8 pf[2];
#pragma unroll
    for (int is = 0; is < 2; ++is) {
      const int ilocI = rg * 32 + is * 16 + lr; // 0..63
#pragma unroll
      for (int nt2 = 0; nt2 < 2; ++nt2) {
        int jl = jh * 32 + lq * 8 + nt2 * 4;
        int Xm3 = 124 + ilocI - jl;
        int ph = Xm3 & 3, b0 = Xm3 & ~3;
        f32x4 cv = *(const f32x4*)(cumB + ph * 200 + b0);
        if (!diag) {
#pragma unroll
          for (int r = 0; r < 4; ++r)
            pf[is][nt2 * 4 + r] =
                bf16bits(exp2f(sa[is][nt2][r] * SCALE2 + cv[3 - r]));
        } else {
#pragma unroll
          for (int r = 0; r < 4; ++r) {
            float pv = (doff + ilocI - jl - r >= 0)
                           ? exp2f(sa[is][nt2][r] * SCALE2 + cv[3 - r])
                           : 0.f;
            pf[is][nt2 * 4 + r] = bf16bits(pv);
          }
        }
      }
    }

    // O += P V; l += P 1 — pf straight from registers; vf shared across is.
    lacc[0] = MFMA16(pf[0], ones, lacc[0]);
    lacc[1] = MFMA16(pf[1], ones, lacc[1]);
#pragma unroll
    for (int dt = 0; dt < 4; ++dt) {
      int vrow = dt * 16 + lr;
      bf16x8 vf = *(const bf16x8*)(vb + vrow * 256 +
                      (((jh * 4 + lq) ^ (vrow & 15)) << 4));
      oacc[0][dt] = MFMA16(pf[0], vf, oacc[0][dt]);
      oacc[1][dt] = MFMA16(pf[1], vf, oacc[1][dt]);
    }

    if (diag) {
      // tile end: combine the 4 j-quarters per rg (additive — no-max exp2
      // softmax). Pairwise tree through the consumed K/V buffer:
      // 2 rg x 2 slots x (2 is x 4 dt x 64 lanes x 16B) = 32KB exactly.
      __syncthreads();   // all reads of buf bsel complete
      f32x4* scrq = (f32x4*)(smem + bsel * 32768) + rg * 1024;
      if (jh == 1 || jh == 3) {
        f32x4* dst = scrq + (jh == 1 ? 0 : 512);
#pragma unroll
        for (int is = 0; is < 2; ++is)
#pragma unroll
          for (int dt = 0; dt < 4; ++dt)
            dst[(is * 4 + dt) * 64 + lane] = oacc[is][dt];
      }
      if (jh >= 1 && lr == 0) {
#pragma unroll
        for (int is = 0; is < 2; ++is)
#pragma unroll
          for (int r = 0; r < 4; ++r)
            combL[(rg * 3 + jh - 1) * 32 + is * 16 + lq * 4 + r] = lacc[is][r];
      }
      __syncthreads();
      if (jh == 0) {
#pragma unroll
        for (int is = 0; is < 2; ++is)
#pragma unroll
          for (int dt = 0; dt < 4; ++dt)
            oacc[is][dt] += scrq[(is * 4 + dt) * 64 + lane];
      } else if (jh == 2) {
#pragma unroll
        for (int is = 0; is < 2; ++is)
#pragma unroll
          for (int dt = 0; dt < 4; ++dt)
            oacc[is][dt] += scrq[512 + (is * 4 + dt) * 64 + lane];
      }
      __syncthreads();
      if (jh == 2) {
#pragma unroll
        for (int is = 0; is < 2; ++is)
#pragma unroll
          for (int dt = 0; dt < 4; ++dt)
            scrq[(is * 4 + dt) * 64 + lane] = oacc[is][dt];
      }
      __syncthreads();
      if (jh == 0) {
#pragma unroll
        for (int is = 0; is < 2; ++is) {
#pragma unroll
          for (int dt = 0; dt < 4; ++dt)
            oacc[is][dt] += scrq[(is * 4 + dt) * 64 + lane];
#pragma unroll
          for (int r = 0; r < 4; ++r)
            lacc[is][r] += combL[(rg * 3 + 0) * 32 + is * 16 + lq * 4 + r] +
                           combL[(rg * 3 + 1) * 32 + is * 16 + lq * 4 + r] +
                           combL[(rg * 3 + 2) * 32 + is * 16 + lq * 4 + r];
        }
        // store mix[b][s][n][d] for this rg's 32 rows
#pragma unroll
        for (int is = 0; is < 2; ++is)
#pragma unroll
          for (int dt = 0; dt < 4; ++dt)
#pragma unroll
            for (int r = 0; r < 4; ++r) {
              int i = i0 + rg * 32 + is * 16 + lq * 4 + r;
              int d = dt * 16 + lr;
              mix[((size_t)(b * S_ + i) * NH + n) * DH + d] =
                  __float2bfloat16(oacc[is][dt][r] / lacc[is][r]);
            }
      }
      jt = 0; i0 = T1 * 64; nu = (T1 + 2) >> 1;  // switch to light tile
    } else {
      ++jt;
    }
  }
}

// ---------------------------------------------------------------------------
extern "C" void kernel_launch(void* const* d_in, const int* in_sizes, int n_in,
                              void* d_out, int out_size, void* d_ws, size_t ws_size,
                              hipStream_t stream) {
  const float* x     = (const float*)d_in[0];   // [B,S,H] f32
  const float* qkv   = (const float*)d_in[1];   // [H,3,N,D] f32 == [1024][3072]
  const float* out_w = (const float*)d_in[2];   // [N,D,H] f32   == [1024][1024]
  const float* rpe   = (const float*)d_in[3];   // [N,S] f32
  float* out = (float*)d_out;                   // [B,S,H] f32

  char* ws = (char*)d_ws;
  bf16* qkvT  = (bf16*)(ws + 0);          // [3072][1024] bf16   6291456 B
  bf16* outwT = (bf16*)(ws + 6291456);    // [1024][1024] bf16   2097152 B
  bf16* xb    = (bf16*)(ws + 8388608);    // [4096][1024] bf16   8388608 B
  bf16* qb    = (bf16*)(ws + 16777216);   // [bn][S][D]          8388608 B
  bf16* kb    = (bf16*)(ws + 25165824);   // [bn][S][D]          8388608 B
  bf16* vtb   = (bf16*)(ws + 33554432);   // [bn][D][S]          8388608 B
  bf16* mixb  = (bf16*)(ws + 41943040);   // [b][s][n][d]        8388608 B
  float* cum  = (float*)(ws + 50331648);  // [N][CUMROW] f32      139520 B

  // 1. fused prep: convert x, transpose+convert weights, padded rpe cumsum
  prep<<<8208, 256, 0, stream>>>(x, xb, qkv, qkvT, out_w, outwT, rpe, cum);
  // 2. QKV projection (V written pre-transposed; 768 blocks = 3/CU)
  gemm_bt<0><<<dim3(3072 / 128, 4096 / 128), 256, 0, stream>>>(xb, qkvT, qb, kb, vtb, nullptr);
  // 3. attention: 512 blocks x 512 threads (8 waves) = 2 blocks/CU =
  //    16 waves/CU; 17 64x128-units each; in-reg P; LDS-staged bias
  fa_kernel<<<512, 512, 0, stream>>>(qb, kb, vtb, cum, mixb);
  // 4. output projection (f32 out; 128x64 tiles -> 512 blocks = 2/CU)
  gemm_bt<1><<<dim3(1024 / 64, 4096 / 128), 256, 0, stream>>>(mixb, outwT, nullptr, nullptr, nullptr, out);
}

// Round 12
// 181.293 us; speedup vs baseline: 1.0438x; 1.0064x over previous
//
#include <hip/hip_runtime.h>
#include <hip/hip_bf16.h>
#include <cstdint>
#include <cstddef>

// Problem constants
#define B_   2
#define S_   2048
#define H_   1024
#define NH   16
#define DH   64
#define LOG2E 1.4426950408889634f
#define SCALE2 (0.125f * LOG2E)   // D^-0.5 * log2(e): softmax done in exp2 domain
#define CUMPAD 132                // zero-pad floats before cum row (kept from R9)
#define CUMROW (CUMPAD + S_)      // 2180 floats per head row

typedef __hip_bfloat16 bf16;
typedef short bf16x8 __attribute__((ext_vector_type(8)));   // 8 bf16 in 4 VGPRs
typedef float f32x4 __attribute__((ext_vector_type(4)));

#define MFMA16(a, b, c) __builtin_amdgcn_mfma_f32_16x16x32_bf16((a), (b), (c), 0, 0, 0)

__device__ __forceinline__ void async16(const void* g, void* l) {
  __builtin_amdgcn_global_load_lds(
      (const __attribute__((address_space(1))) void*)g,
      (__attribute__((address_space(3))) void*)l,
      16, 0, 0);
}
__device__ __forceinline__ void async4(const void* g, void* l) {
  __builtin_amdgcn_global_load_lds(
      (const __attribute__((address_space(1))) void*)g,
      (__attribute__((address_space(3))) void*)l,
      4, 0, 0);
}

__device__ __forceinline__ short bf16bits(float v) {
  bf16 t = __float2bfloat16(v);
  return *reinterpret_cast<short*>(&t);
}

// ---------------------------------------------------------------------------
// Fused prep kernel (one dispatch, grid 8208) — unchanged from R10.
// ---------------------------------------------------------------------------
__device__ __forceinline__ void tr_body(const float* __restrict__ src,
                                        bf16* __restrict__ dst, int R, int C,
                                        int c0, int r0, bf16 (*tile)[33], int tid) {
  int tx = tid & 31, ty = tid >> 5;   // 32 x 8
  for (int i = 0; i < 32; i += 8)
    tile[ty + i][tx] = __float2bfloat16(src[(size_t)(r0 + ty + i) * C + c0 + tx]);
  __syncthreads();
  for (int i = 0; i < 32; i += 8)
    dst[(size_t)(c0 + ty + i) * R + r0 + tx] = tile[tx][ty + i];
}

__global__ __launch_bounds__(256)
void prep(const float* __restrict__ x, bf16* __restrict__ xb,
          const float* __restrict__ qkv, bf16* __restrict__ qkvT,
          const float* __restrict__ outw, bf16* __restrict__ outwT,
          const float* __restrict__ rpe, float* __restrict__ cum) {
  __shared__ char pm[2176] __attribute__((aligned(16)));
  const int L = blockIdx.x, tid = threadIdx.x;
  if (L < 4096) {
    int i = (L * 256 + tid) * 4;
    float4 v = *(const float4*)(x + i);
    bf16 o[4] = {__float2bfloat16(v.x), __float2bfloat16(v.y),
                 __float2bfloat16(v.z), __float2bfloat16(v.w)};
    *(uint64_t*)(xb + i) = *(const uint64_t*)o;
  } else if (L < 7168) {
    int t = L - 4096;
    int cx = t % 96, ry = t / 96;
    tr_body(qkv, qkvT, 1024, 3072, cx * 32, ry * 32, (bf16(*)[33])pm, tid);
  } else if (L < 8192) {
    int t = L - 7168;
    int cx = t & 31, ry = t >> 5;
    tr_body(outw, outwT, 1024, 1024, cx * 32, ry * 32, (bf16(*)[33])pm, tid);
  } else {
    // rpe cumsum (scaled by LOG2E) into padded row
    float* ssum = (float*)pm;
    int n = L - 8192;
    float* crow = cum + (size_t)n * CUMROW;
    if (tid < CUMPAD) crow[tid] = 0.f;          // zero the pad
    float loc[8];
    float s = 0.f;
    int base = tid * 8;
#pragma unroll
    for (int u = 0; u < 8; ++u) {
      loc[u] = rpe[n * S_ + base + u];
      s += loc[u];
    }
    ssum[tid] = s;
    __syncthreads();
    float own = s;
    for (int off = 1; off < 256; off <<= 1) {
      float v = (tid >= off) ? ssum[tid - off] : 0.f;
      __syncthreads();
      ssum[tid] += v;
      __syncthreads();
    }
    float run = ssum[tid] - own;   // exclusive prefix of this thread's chunk
#pragma unroll
    for (int u = 0; u < 8; ++u) {
      run += loc[u];
      crow[CUMPAD + base + u] = run * LOG2E;
    }
  }
}

// ---------------------------------------------------------------------------
// GEMM — unchanged from R8/R10.
// ---------------------------------------------------------------------------
template <int MODE>
__global__ __launch_bounds__(256, MODE == 0 ? 3 : 2)
void gemm_bt(const bf16* __restrict__ A, const bf16* __restrict__ Bt,
             bf16* __restrict__ C0, bf16* __restrict__ C1, bf16* __restrict__ C2,
             float* __restrict__ F0) {
  constexpr int NT = (MODE == 0) ? 4 : 2;     // n-subtiles per wave
  constexpr int NB = NT * 32;                 // block n-extent: 128 or 64
  constexpr int BUFSZ = 8192 + NB * 64;       // A 8KB + B NB*32*2B
  __shared__ char smem[MODE == 0 ? 36864 : 24576] __attribute__((aligned(16)));
  const int tid = threadIdx.x, lane = tid & 63, w = tid >> 6;
  const int lr = lane & 15, lq = lane >> 4;
  const int m0 = blockIdx.y * 128, n0 = blockIdx.x * NB;
  const int wm = (w & 1) * 64, wn = (w >> 1) * (NT * 16);

  f32x4 acc[4][NT] = {};

  auto stage = [&](int buf, int k0) {
    char* dst = smem + buf * BUFSZ;
#pragma unroll
    for (int t = 0; t < 2; ++t) {
      int c = t * 256 + tid;
      int row = c >> 2, ch = c & 3;
      int k8 = (ch ^ ((row >> 1) & 3)) * 8;
      async16(A + (size_t)(m0 + row) * 1024 + k0 + k8, dst + c * 16);
    }
#pragma unroll
    for (int t = 0; t < NB / 64; ++t) {
      int c = t * 256 + tid;
      int row = c >> 2, ch = c & 3;
      int k8 = (ch ^ ((row >> 1) & 3)) * 8;
      async16(Bt + (size_t)(n0 + row) * 1024 + k0 + k8, dst + 8192 + c * 16);
    }
  };

  stage(0, 0);

  for (int s = 0; s < 32; ++s) {
    const int bsel = s & 1;
    __syncthreads();
    if (s + 1 < 32) stage(bsel ^ 1, (s + 1) * 32);

    const bf16* As = (const bf16*)(smem + bsel * BUFSZ);
    const bf16* Bs = (const bf16*)(smem + bsel * BUFSZ + 8192);
    bf16x8 af[4], bfr[NT];
#pragma unroll
    for (int mt = 0; mt < 4; ++mt) {
      int row = wm + mt * 16 + lr;
      af[mt] = *(const bf16x8*)(As + row * 32 + ((lq ^ ((row >> 1) & 3)) << 3));
    }
#pragma unroll
    for (int nt = 0; nt < NT; ++nt) {
      int row = wn + nt * 16 + lr;
      bfr[nt] = *(const bf16x8*)(Bs + row * 32 + ((lq ^ ((row >> 1) & 3)) << 3));
    }
#pragma unroll
    for (int mt = 0; mt < 4; ++mt)
#pragma unroll
      for (int nt = 0; nt < NT; ++nt)
        acc[mt][nt] = MFMA16(af[mt], bfr[nt], acc[mt][nt]);
  }

  if (MODE == 0) {
    __syncthreads();   // all As/Bs reads done; reuse LDS for epilogue tiles
    bf16* E = (bf16*)smem + w * (64 * 72);   // wave-private [64][72]
    const int cbase = n0 + wn;               // 64-aligned
    const int mm = cbase >> 10, nn = (cbase >> 6) & 15;
    const int bb = (m0 + wm) >> 11;
    const int sbase = (m0 + wm) & 2047;
    if (mm < 2) {
#pragma unroll
      for (int mt = 0; mt < 4; ++mt)
#pragma unroll
        for (int nt = 0; nt < 4; ++nt)
#pragma unroll
          for (int r = 0; r < 4; ++r)
            E[(mt * 16 + lq * 4 + r) * 72 + nt * 16 + lr] =
                __float2bfloat16(acc[mt][nt][r]);
      bf16* dst = (mm == 0 ? C0 : C1) +
                  ((size_t)(bb * NH + nn) * S_ + sbase) * DH;
#pragma unroll
      for (int it = 0; it < 8; ++it) {
        int c = it * 64 + lane;
        int rw = c >> 3, c8 = c & 7;
        *(uint4*)(dst + (size_t)rw * DH + c8 * 8) =
            *(const uint4*)(E + rw * 72 + c8 * 8);
      }
    } else {
#pragma unroll
      for (int mt = 0; mt < 4; ++mt)
#pragma unroll
        for (int nt = 0; nt < 4; ++nt)
#pragma unroll
          for (int r = 0; r < 4; ++r)
            E[(nt * 16 + lr) * 72 + mt * 16 + lq * 4 + r] =
                __float2bfloat16(acc[mt][nt][r]);
      bf16* dst = C2 + (size_t)(bb * NH + nn) * DH * S_;
#pragma unroll
      for (int it = 0; it < 8; ++it) {
        int c = it * 64 + lane;
        int dr = c >> 3, c8 = c & 7;
        *(uint4*)(dst + (size_t)dr * S_ + sbase + c8 * 8) =
            *(const uint4*)(E + dr * 72 + c8 * 8);
      }
    }
  } else {
#pragma unroll
    for (int mt = 0; mt < 4; ++mt)
#pragma unroll
      for (int nt = 0; nt < NT; ++nt)
#pragma unroll
        for (int r = 0; r < 4; ++r) {
          int rM = m0 + wm + mt * 16 + lq * 4 + r;
          int cN = n0 + wn + nt * 16 + lr;
          F0[(size_t)rM * 1024 + cN] = acc[mt][nt][r];
        }
  }
}

// ---------------------------------------------------------------------------
// Flash attention, R12: R11 (16 waves/CU, 512-thread blocks) with the
// REGISTER BUDGET PINNED. R11's regression mechanism: __launch_bounds__
// only sets MIN waves/EU; the backend's occupancy heuristic targeted 8
// waves/EU -> capped VGPR at 64 (live state ~100) -> spilled oacc/qf to
// scratch every unit (WRITE_SIZE 8.2->23.5 MB, FETCH +8 MB — the spill
// signature). Fix: amdgpu_waves_per_eu(4,4) pins min=max=4 waves/EU ->
// VGPR budget exactly 128, no spills, 2 blocks/CU x 8 waves = 16 waves/CU.
// Everything else identical to R11: pair {31-p,p} = 17 units; wave = 32
// Q-rows x 32 j-cols (2 rg x 4 jh); in-reg P via permuted K rows; dbuf +
// prefetch-after-barrier; LDS-staged 4-phase bias windows (stride 200);
// pairwise j-combine per rg through the consumed K/V buffer.
// LDS: K/V dbuf [0,65536); cum [2][4][200] f32 [65536,71936);
//      combL [2][3][32] f32 [71936,72704). 72704 x 2 = 145.4 KB <= 160 KB.
// ---------------------------------------------------------------------------
__device__ __forceinline__ void fa_stage(const bf16* __restrict__ k,
                                         const bf16* __restrict__ vt,
                                         const float* __restrict__ cumn,
                                         char* smem, int bn, int i0, int jb,
                                         int buf, int tid) {
  char* dst = smem + buf * 32768;
  // K tile: rows jb..jb+127 (128B each, 8 chunks); slot (row,ch) holds
  // global chunk ch^kk(row), kk = (row&3)|((row>>1)&4). 1024 chunks.
  const char* ksrc = (const char*)(k + ((size_t)bn * S_ + jb) * DH);
#pragma unroll
  for (int t = 0; t < 2; ++t) {
    int c = t * 512 + tid;
    int row = c >> 3, ch = c & 7;
    int cs = ch ^ ((row & 3) | ((row >> 1) & 4));
    async16(ksrc + row * 128 + cs * 16, dst + c * 16);
  }
  // Vt tile: d rows 0..63, cols jb..jb+127 (256B, 16 chunks); slot (d,ch)
  // holds global chunk ch^(d&15). 1024 chunks.
  const char* vsrc = (const char*)(vt + (size_t)bn * DH * S_);
#pragma unroll
  for (int t = 0; t < 2; ++t) {
    int c = t * 512 + tid;
    int row = c >> 4, ch = c & 15;            // row = d index
    int cs = ch ^ (row & 15);
    async16(vsrc + (size_t)row * (S_ * 2) + jb * 2 + cs * 16,
            dst + 16384 + c * 16);
  }
  // cum windows: win[t] = cumn[clamp(i0-jb-127+t)], t<194; 4 phases,
  // stride 200 words (== 8 mod 32 banks). (R7-proven mechanism.)
  if (tid < 194) {
    float* cdst = (float*)(smem + 65536) + buf * 800;  // 4*200
    int base = i0 - jb - 127 + tid;
#pragma unroll
    for (int p = 0; p < 4; ++p) {
      int src = base + p;
      src = src < 0 ? 0 : (src > S_ - 1 ? S_ - 1 : src);
      async4(cumn + src, cdst + p * 200 + tid);
    }
  }
}

__global__ __launch_bounds__(512)
__attribute__((amdgpu_waves_per_eu(4, 4)))
void fa_kernel(const bf16* __restrict__ q, const bf16* __restrict__ k,
               const bf16* __restrict__ vt, const float* __restrict__ cum,
               bf16* __restrict__ mix) {
  __shared__ char smem[72704] __attribute__((aligned(16)));
  float* combL = (float*)(smem + 71936);        // [2 rg][3][32]

  const int tid = threadIdx.x, lane = tid & 63, w = tid >> 6;  // w: 0..7
  const int lr = lane & 15, lq = lane >> 4;
  const int jh = w & 3, rg = w >> 2;            // j-quarter (32 cols), row-grp

  const int L = blockIdx.x;                     // 0..511
  const int xcd = L & 7, slot = L >> 3;         // slot 0..63
  const int bn = xcd + 8 * (slot & 3);          // 4 heads per XCD
  const int pp = slot >> 2;                     // pair index 0..15
  const int n = bn & (NH - 1);
  const int b = bn >> 4;
  const float* cumn = cum + (size_t)n * CUMROW + CUMPAD;

  const int T0 = 31 - pp;                       // heavy tile
  const int T1 = pp;                            // light tile
  const int nu0 = (T0 + 2) >> 1;                // units in tile 0

  // all-ones B fragment for the l row-sum MFMA
  bf16x8 ones;
#pragma unroll
  for (int u = 0; u < 8; ++u) ones[u] = (short)0x3F80;
  const f32x4 fz = {0.f, 0.f, 0.f, 0.f};

  // permuted-K swizzle key (independent of kd/nt2/jh)
  const int kkey = (lr & 3) | (((lr >> 2) & 1) << 2);

  bf16x8 qf[2][2];                              // [is][kd]
  f32x4 oacc[2][4];                             // [is][dt]
  f32x4 lacc[2];

  // prologue: stage unit 0 (tile T0, jt 0) into buf 0
  fa_stage(k, vt, cumn, smem, bn, T0 * 64, 0, 0, tid);

  int jt = 0, i0 = T0 * 64, nu = nu0;

  for (int g = 0; g < 17; ++g) {
    const int bsel = g & 1;
    const char* kb = smem + bsel * 32768;
    const char* vb = kb + 16384;
    const float* cumB = (const float*)(smem + 65536) + bsel * 800;
    const int jb = jt * 128;
    const bool diag = (jt == nu - 1);           // last unit of this tile
    const int doff = i0 - jb;                   // diag: 0 or 64; else >=128

    __syncthreads();   // staged data for g visible; buf^1 prior reads done

    // prefetch unit g+1 into the other buffer (flies during this compute)
    if (g + 1 < 17) {
      int gn = g + 1, tin, jtn;
      if (gn < nu0) { tin = T0; jtn = gn; }
      else          { tin = T1; jtn = gn - nu0; }
      fa_stage(k, vt, cumn, smem, bn, tin * 64, jtn * 128, bsel ^ 1, tid);
    }

    if (jt == 0) {
      // new tile: load Q fragments (B-operand for S^T = K*Q^T), reset acc
      const bf16* qbase = q + ((size_t)bn * S_ + i0 + rg * 32) * DH;
#pragma unroll
      for (int is = 0; is < 2; ++is) {
#pragma unroll
        for (int kd = 0; kd < 2; ++kd)
          qf[is][kd] = *(const bf16x8*)(qbase + (is * 16 + lr) * DH + kd * 32 + lq * 8);
        lacc[is] = fz;
#pragma unroll
        for (int dt = 0; dt < 4; ++dt) oacc[is][dt] = fz;
      }
    }

    // S^T = K * Q^T with PERMUTED K rows over this wave's 32-col chunk.
    // A-row lr of MFMA nt2 loads krow = jh*32 + (lr>>2)*8 + nt2*4 + (lr&3),
    // so C position (lq*4+r) holds j = jh*32 + lq*8 + nt2*4 + r — the PV
    // A-fragment layout. kf shared across the 2 i-subtiles.
    f32x4 sa[2][2] = {};
#pragma unroll
    for (int kd = 0; kd < 2; ++kd)
#pragma unroll
      for (int nt2 = 0; nt2 < 2; ++nt2) {
        int krow = jh * 32 + ((lr >> 2) << 3) + nt2 * 4 + (lr & 3);
        bf16x8 kf = *(const bf16x8*)(kb + krow * 128 +
                        (((kd * 4 + lq) ^ kkey) << 4));
        sa[0][nt2] = MFMA16(kf, qf[0][kd], sa[0][nt2]);
        sa[1][nt2] = MFMA16(kf, qf[1][kd], sa[1][nt2]);
      }

    // p = exp2(s*SCALE2 + cum[i-j]) straight into PV A-fragments.
    // One b128 bias read per reg-quad from the staged window:
    // Xm3 = 124 + ilocI - jl in [0,187]; cv[m] = win[Xm3+m]; bias(r)=cv[3-r].
    bf16x8 pf[2];
#pragma unroll
    for (int is = 0; is < 2; ++is) {
      const int ilocI = rg * 32 + is * 16 + lr; // 0..63
#pragma unroll
      for (int nt2 = 0; nt2 < 2; ++nt2) {
        int jl = jh * 32 + lq * 8 + nt2 * 4;
        int Xm3 = 124 + ilocI - jl;
        int ph = Xm3 & 3, b0 = Xm3 & ~3;
        f32x4 cv = *(const f32x4*)(cumB + ph * 200 + b0);
        if (!diag) {
#pragma unroll
          for (int r = 0; r < 4; ++r)
            pf[is][nt2 * 4 + r] =
                bf16bits(exp2f(sa[is][nt2][r] * SCALE2 + cv[3 - r]));
        } else {
#pragma unroll
          for (int r = 0; r < 4; ++r) {
            float pv = (doff + ilocI - jl - r >= 0)
                           ? exp2f(sa[is][nt2][r] * SCALE2 + cv[3 - r])
                           : 0.f;
            pf[is][nt2 * 4 + r] = bf16bits(pv);
          }
        }
      }
    }

    // O += P V; l += P 1 — pf straight from registers; vf shared across is.
    lacc[0] = MFMA16(pf[0], ones, lacc[0]);
    lacc[1] = MFMA16(pf[1], ones, lacc[1]);
#pragma unroll
    for (int dt = 0; dt < 4; ++dt) {
      int vrow = dt * 16 + lr;
      bf16x8 vf = *(const bf16x8*)(vb + vrow * 256 +
                      (((jh * 4 + lq) ^ (vrow & 15)) << 4));
      oacc[0][dt] = MFMA16(pf[0], vf, oacc[0][dt]);
      oacc[1][dt] = MFMA16(pf[1], vf, oacc[1][dt]);
    }

    if (diag) {
      // tile end: combine the 4 j-quarters per rg (additive — no-max exp2
      // softmax). Pairwise tree through the consumed K/V buffer:
      // 2 rg x 2 slots x (2 is x 4 dt x 64 lanes x 16B) = 32KB exactly.
      __syncthreads();   // all reads of buf bsel complete
      f32x4* scrq = (f32x4*)(smem + bsel * 32768) + rg * 1024;
      if (jh == 1 || jh == 3) {
        f32x4* dst = scrq + (jh == 1 ? 0 : 512);
#pragma unroll
        for (int is = 0; is < 2; ++is)
#pragma unroll
          for (int dt = 0; dt < 4; ++dt)
            dst[(is * 4 + dt) * 64 + lane] = oacc[is][dt];
      }
      if (jh >= 1 && lr == 0) {
#pragma unroll
        for (int is = 0; is < 2; ++is)
#pragma unroll
          for (int r = 0; r < 4; ++r)
            combL[(rg * 3 + jh - 1) * 32 + is * 16 + lq * 4 + r] = lacc[is][r];
      }
      __syncthreads();
      if (jh == 0) {
#pragma unroll
        for (int is = 0; is < 2; ++is)
#pragma unroll
          for (int dt = 0; dt < 4; ++dt)
            oacc[is][dt] += scrq[(is * 4 + dt) * 64 + lane];
      } else if (jh == 2) {
#pragma unroll
        for (int is = 0; is < 2; ++is)
#pragma unroll
          for (int dt = 0; dt < 4; ++dt)
            oacc[is][dt] += scrq[512 + (is * 4 + dt) * 64 + lane];
      }
      __syncthreads();
      if (jh == 2) {
#pragma unroll
        for (int is = 0; is < 2; ++is)
#pragma unroll
          for (int dt = 0; dt < 4; ++dt)
            scrq[(is * 4 + dt) * 64 + lane] = oacc[is][dt];
      }
      __syncthreads();
      if (jh == 0) {
#pragma unroll
        for (int is = 0; is < 2; ++is) {
#pragma unroll
          for (int dt = 0; dt < 4; ++dt)
            oacc[is][dt] += scrq[(is * 4 + dt) * 64 + lane];
#pragma unroll
          for (int r = 0; r < 4; ++r)
            lacc[is][r] += combL[(rg * 3 + 0) * 32 + is * 16 + lq * 4 + r] +
                           combL[(rg * 3 + 1) * 32 + is * 16 + lq * 4 + r] +
                           combL[(rg * 3 + 2) * 32 + is * 16 + lq * 4 + r];
        }
        // store mix[b][s][n][d] for this rg's 32 rows
#pragma unroll
        for (int is = 0; is < 2; ++is)
#pragma unroll
          for (int dt = 0; dt < 4; ++dt)
#pragma unroll
            for (int r = 0; r < 4; ++r) {
              int i = i0 + rg * 32 + is * 16 + lq * 4 + r;
              int d = dt * 16 + lr;
              mix[((size_t)(b * S_ + i) * NH + n) * DH + d] =
                  __float2bfloat16(oacc[is][dt][r] / lacc[is][r]);
            }
      }
      jt = 0; i0 = T1 * 64; nu = (T1 + 2) >> 1;  // switch to light tile
    } else {
      ++jt;
    }
  }
}

// ---------------------------------------------------------------------------
extern "C" void kernel_launch(void* const* d_in, const int* in_sizes, int n_in,
                              void* d_out, int out_size, void* d_ws, size_t ws_size,
                              hipStream_t stream) {
  const float* x     = (const float*)d_in[0];   // [B,S,H] f32
  const float* qkv   = (const float*)d_in[1];   // [H,3,N,D] f32 == [1024][3072]
  const float* out_w = (const float*)d_in[2];   // [N,D,H] f32   == [1024][1024]
  const float* rpe   = (const float*)d_in[3];   // [N,S] f32
  float* out = (float*)d_out;                   // [B,S,H] f32

  char* ws = (char*)d_ws;
  bf16* qkvT  = (bf16*)(ws + 0);          // [3072][1024] bf16   6291456 B
  bf16* outwT = (bf16*)(ws + 6291456);    // [1024][1024] bf16   2097152 B
  bf16* xb    = (bf16*)(ws + 8388608);    // [4096][1024] bf16   8388608 B
  bf16* qb    = (bf16*)(ws + 16777216);   // [bn][S][D]          8388608 B
  bf16* kb    = (bf16*)(ws + 25165824);   // [bn][S][D]          8388608 B
  bf16* vtb   = (bf16*)(ws + 33554432);   // [bn][D][S]          8388608 B
  bf16* mixb  = (bf16*)(ws + 41943040);   // [b][s][n][d]        8388608 B
  float* cum  = (float*)(ws + 50331648);  // [N][CUMROW] f32      139520 B

  // 1. fused prep: convert x, transpose+convert weights, padded rpe cumsum
  prep<<<8208, 256, 0, stream>>>(x, xb, qkv, qkvT, out_w, outwT, rpe, cum);
  // 2. QKV projection (V written pre-transposed; 768 blocks = 3/CU)
  gemm_bt<0><<<dim3(3072 / 128, 4096 / 128), 256, 0, stream>>>(xb, qkvT, qb, kb, vtb, nullptr);
  // 3. attention: 512 blocks x 512 threads (8 waves), waves_per_eu pinned
  //    4,4 -> VGPR 128, no spills; 16 waves/CU; 17 64x128-units each
  fa_kernel<<<512, 512, 0, stream>>>(qb, kb, vtb, cum, mixb);
  // 4. output projection (f32 out; 128x64 tiles -> 512 blocks = 2/CU)
  gemm_bt<1><<<dim3(1024 / 64, 4096 / 128), 256, 0, stream>>>(mixb, outwT, nullptr, nullptr, nullptr, out);
}

// Round 13
// 178.939 us; speedup vs baseline: 1.0575x; 1.0132x over previous
//
#include <hip/hip_runtime.h>
#include <hip/hip_bf16.h>
#include <cstdint>
#include <cstddef>

// Problem constants
#define B_   2
#define S_   2048
#define H_   1024
#define NH   16
#define DH   64
#define LOG2E 1.4426950408889634f
#define SCALE2 (0.125f * LOG2E)   // D^-0.5 * log2(e): softmax done in exp2 domain
#define CUMPAD 132                // zero-pad floats before cum row
#define CUMROW (CUMPAD + S_)      // 2180 floats per head row

typedef __hip_bfloat16 bf16;
typedef short bf16x8 __attribute__((ext_vector_type(8)));   // 8 bf16 in 4 VGPRs
typedef float f32x4 __attribute__((ext_vector_type(4)));

#define MFMA16(a, b, c) __builtin_amdgcn_mfma_f32_16x16x32_bf16((a), (b), (c), 0, 0, 0)

__device__ __forceinline__ void async16(const void* g, void* l) {
  __builtin_amdgcn_global_load_lds(
      (const __attribute__((address_space(1))) void*)g,
      (__attribute__((address_space(3))) void*)l,
      16, 0, 0);
}
__device__ __forceinline__ void async4(const void* g, void* l) {
  __builtin_amdgcn_global_load_lds(
      (const __attribute__((address_space(1))) void*)g,
      (__attribute__((address_space(3))) void*)l,
      4, 0, 0);
}

__device__ __forceinline__ short bf16bits(float v) {
  bf16 t = __float2bfloat16(v);
  return *reinterpret_cast<short*>(&t);
}

// ---------------------------------------------------------------------------
// Fused prep kernel (one dispatch, grid 8208) — unchanged.
// ---------------------------------------------------------------------------
__device__ __forceinline__ void tr_body(const float* __restrict__ src,
                                        bf16* __restrict__ dst, int R, int C,
                                        int c0, int r0, bf16 (*tile)[33], int tid) {
  int tx = tid & 31, ty = tid >> 5;   // 32 x 8
  for (int i = 0; i < 32; i += 8)
    tile[ty + i][tx] = __float2bfloat16(src[(size_t)(r0 + ty + i) * C + c0 + tx]);
  __syncthreads();
  for (int i = 0; i < 32; i += 8)
    dst[(size_t)(c0 + ty + i) * R + r0 + tx] = tile[tx][ty + i];
}

__global__ __launch_bounds__(256)
void prep(const float* __restrict__ x, bf16* __restrict__ xb,
          const float* __restrict__ qkv, bf16* __restrict__ qkvT,
          const float* __restrict__ outw, bf16* __restrict__ outwT,
          const float* __restrict__ rpe, float* __restrict__ cum) {
  __shared__ char pm[2176] __attribute__((aligned(16)));
  const int L = blockIdx.x, tid = threadIdx.x;
  if (L < 4096) {
    int i = (L * 256 + tid) * 4;
    float4 v = *(const float4*)(x + i);
    bf16 o[4] = {__float2bfloat16(v.x), __float2bfloat16(v.y),
                 __float2bfloat16(v.z), __float2bfloat16(v.w)};
    *(uint64_t*)(xb + i) = *(const uint64_t*)o;
  } else if (L < 7168) {
    int t = L - 4096;
    int cx = t % 96, ry = t / 96;
    tr_body(qkv, qkvT, 1024, 3072, cx * 32, ry * 32, (bf16(*)[33])pm, tid);
  } else if (L < 8192) {
    int t = L - 7168;
    int cx = t & 31, ry = t >> 5;
    tr_body(outw, outwT, 1024, 1024, cx * 32, ry * 32, (bf16(*)[33])pm, tid);
  } else {
    // rpe cumsum (scaled by LOG2E) into padded row
    float* ssum = (float*)pm;
    int n = L - 8192;
    float* crow = cum + (size_t)n * CUMROW;
    if (tid < CUMPAD) crow[tid] = 0.f;          // zero the pad
    float loc[8];
    float s = 0.f;
    int base = tid * 8;
#pragma unroll
    for (int u = 0; u < 8; ++u) {
      loc[u] = rpe[n * S_ + base + u];
      s += loc[u];
    }
    ssum[tid] = s;
    __syncthreads();
    float own = s;
    for (int off = 1; off < 256; off <<= 1) {
      float v = (tid >= off) ? ssum[tid - off] : 0.f;
      __syncthreads();
      ssum[tid] += v;
      __syncthreads();
    }
    float run = ssum[tid] - own;   // exclusive prefix of this thread's chunk
#pragma unroll
    for (int u = 0; u < 8; ++u) {
      run += loc[u];
      crow[CUMPAD + base + u] = run * LOG2E;
    }
  }
}

// ---------------------------------------------------------------------------
// GEMM — unchanged from R8/R12.
// ---------------------------------------------------------------------------
template <int MODE>
__global__ __launch_bounds__(256, MODE == 0 ? 3 : 2)
void gemm_bt(const bf16* __restrict__ A, const bf16* __restrict__ Bt,
             bf16* __restrict__ C0, bf16* __restrict__ C1, bf16* __restrict__ C2,
             float* __restrict__ F0) {
  constexpr int NT = (MODE == 0) ? 4 : 2;     // n-subtiles per wave
  constexpr int NB = NT * 32;                 // block n-extent: 128 or 64
  constexpr int BUFSZ = 8192 + NB * 64;       // A 8KB + B NB*32*2B
  __shared__ char smem[MODE == 0 ? 36864 : 24576] __attribute__((aligned(16)));
  const int tid = threadIdx.x, lane = tid & 63, w = tid >> 6;
  const int lr = lane & 15, lq = lane >> 4;
  const int m0 = blockIdx.y * 128, n0 = blockIdx.x * NB;
  const int wm = (w & 1) * 64, wn = (w >> 1) * (NT * 16);

  f32x4 acc[4][NT] = {};

  auto stage = [&](int buf, int k0) {
    char* dst = smem + buf * BUFSZ;
#pragma unroll
    for (int t = 0; t < 2; ++t) {
      int c = t * 256 + tid;
      int row = c >> 2, ch = c & 3;
      int k8 = (ch ^ ((row >> 1) & 3)) * 8;
      async16(A + (size_t)(m0 + row) * 1024 + k0 + k8, dst + c * 16);
    }
#pragma unroll
    for (int t = 0; t < NB / 64; ++t) {
      int c = t * 256 + tid;
      int row = c >> 2, ch = c & 3;
      int k8 = (ch ^ ((row >> 1) & 3)) * 8;
      async16(Bt + (size_t)(n0 + row) * 1024 + k0 + k8, dst + 8192 + c * 16);
    }
  };

  stage(0, 0);

  for (int s = 0; s < 32; ++s) {
    const int bsel = s & 1;
    __syncthreads();
    if (s + 1 < 32) stage(bsel ^ 1, (s + 1) * 32);

    const bf16* As = (const bf16*)(smem + bsel * BUFSZ);
    const bf16* Bs = (const bf16*)(smem + bsel * BUFSZ + 8192);
    bf16x8 af[4], bfr[NT];
#pragma unroll
    for (int mt = 0; mt < 4; ++mt) {
      int row = wm + mt * 16 + lr;
      af[mt] = *(const bf16x8*)(As + row * 32 + ((lq ^ ((row >> 1) & 3)) << 3));
    }
#pragma unroll
    for (int nt = 0; nt < NT; ++nt) {
      int row = wn + nt * 16 + lr;
      bfr[nt] = *(const bf16x8*)(Bs + row * 32 + ((lq ^ ((row >> 1) & 3)) << 3));
    }
#pragma unroll
    for (int mt = 0; mt < 4; ++mt)
#pragma unroll
      for (int nt = 0; nt < NT; ++nt)
        acc[mt][nt] = MFMA16(af[mt], bfr[nt], acc[mt][nt]);
  }

  if (MODE == 0) {
    __syncthreads();   // all As/Bs reads done; reuse LDS for epilogue tiles
    bf16* E = (bf16*)smem + w * (64 * 72);   // wave-private [64][72]
    const int cbase = n0 + wn;               // 64-aligned
    const int mm = cbase >> 10, nn = (cbase >> 6) & 15;
    const int bb = (m0 + wm) >> 11;
    const int sbase = (m0 + wm) & 2047;
    if (mm < 2) {
#pragma unroll
      for (int mt = 0; mt < 4; ++mt)
#pragma unroll
        for (int nt = 0; nt < 4; ++nt)
#pragma unroll
          for (int r = 0; r < 4; ++r)
            E[(mt * 16 + lq * 4 + r) * 72 + nt * 16 + lr] =
                __float2bfloat16(acc[mt][nt][r]);
      bf16* dst = (mm == 0 ? C0 : C1) +
                  ((size_t)(bb * NH + nn) * S_ + sbase) * DH;
#pragma unroll
      for (int it = 0; it < 8; ++it) {
        int c = it * 64 + lane;
        int rw = c >> 3, c8 = c & 7;
        *(uint4*)(dst + (size_t)rw * DH + c8 * 8) =
            *(const uint4*)(E + rw * 72 + c8 * 8);
      }
    } else {
#pragma unroll
      for (int mt = 0; mt < 4; ++mt)
#pragma unroll
        for (int nt = 0; nt < 4; ++nt)
#pragma unroll
          for (int r = 0; r < 4; ++r)
            E[(nt * 16 + lr) * 72 + mt * 16 + lq * 4 + r] =
                __float2bfloat16(acc[mt][nt][r]);
      bf16* dst = C2 + (size_t)(bb * NH + nn) * DH * S_;
#pragma unroll
      for (int it = 0; it < 8; ++it) {
        int c = it * 64 + lane;
        int dr = c >> 3, c8 = c & 7;
        *(uint4*)(dst + (size_t)dr * S_ + sbase + c8 * 8) =
            *(const uint4*)(E + dr * 72 + c8 * 8);
      }
    }
  } else {
#pragma unroll
    for (int mt = 0; mt < 4; ++mt)
#pragma unroll
      for (int nt = 0; nt < NT; ++nt)
#pragma unroll
        for (int r = 0; r < 4; ++r) {
          int rM = m0 + wm + mt * 16 + lq * 4 + r;
          int cN = n0 + wn + nt * 16 + lr;
          F0[(size_t)rM * 1024 + cN] = acc[mt][nt][r];
        }
  }
}

// ---------------------------------------------------------------------------
// Flash attention, R13: FIT THE 64-VGPR BUDGET instead of fighting the
// allocator (R11/R12: launch_bounds and waves_per_eu both ignored -> VGPR
// capped 64, ~100 live -> spills, WRITE 23.5MB). Per-wave state halved:
// 32-row Q-tiles, 64-col KV units, 4 waves = 2 rg(16 rows) x 2 jh(32 cols).
// Live state ~55-65 VGPR -> fits any budget, spills impossible.
// 16 waves/CU via BLOCKS: LDS 36.2KB -> 4 blocks/CU; grid 1024 = exactly
// 4/CU. Equal duration: units(ti) = ceil((ti+1)/2), pair {63-p, p} = 33
// units for every p -> 1024 identical blocks.
// Carried over: permuted-K in-reg P (kkey indep of kd/nt2/jh), dbuf +
// prefetch-after-barrier, LDS 4-phase bias windows (stride 104 == 8 mod
// 32 banks; Xm3 = 60+iloc-jl in [0,91]; CUMPAD absorbs negative indices),
// 2-barrier jh-combine through the consumed K/V buffer.
// q,k: [bn][S][D] bf16;  vt: [bn][D][S] bf16;  cum: [N][CUMROW] f32 padded;
// mix out: [b][s][n][d] bf16
// LDS: K/V dbuf [0,32768) (buf b at b*16384: K 8K, V 8K);
//      cum [2][4][104] f32 [32768,36096); combL [2][16] f32 [36096,36224).
//      36224 x 4 blocks/CU = 144.9 KB <= 160 KB.
// ---------------------------------------------------------------------------
__device__ __forceinline__ void fa_stage(const bf16* __restrict__ k,
                                         const bf16* __restrict__ vt,
                                         const float* __restrict__ cumn,
                                         char* smem, int bn, int i0, int jb,
                                         int buf, int tid) {
  char* dst = smem + buf * 16384;
  // K tile: rows jb..jb+63 (128B each, 8 chunks); slot (row,ch) holds
  // global chunk ch^kk(row), kk = (row&3)|((row>>1)&4). 512 chunks.
  const char* ksrc = (const char*)(k + ((size_t)bn * S_ + jb) * DH);
#pragma unroll
  for (int t = 0; t < 2; ++t) {
    int c = t * 256 + tid;
    int row = c >> 3, ch = c & 7;
    int cs = ch ^ ((row & 3) | ((row >> 1) & 4));
    async16(ksrc + row * 128 + cs * 16, dst + c * 16);
  }
  // Vt tile: d rows 0..63, cols jb..jb+63 (128B, 8 chunks); slot (d,ch)
  // holds global chunk ch^(d&7). 512 chunks.
  const char* vsrc = (const char*)(vt + (size_t)bn * DH * S_);
#pragma unroll
  for (int t = 0; t < 2; ++t) {
    int c = t * 256 + tid;
    int row = c >> 3, ch = c & 7;             // row = d index
    int cs = ch ^ (row & 7);
    async16(vsrc + (size_t)row * (S_ * 2) + jb * 2 + cs * 16,
            dst + 8192 + c * 16);
  }
  // cum windows: win[t] = cumn[i0-jb-63+t] (negatives land in the zero
  // pad; clamp high only). 4 phases, stride 104 (== 8 mod 32 banks).
  if (tid < 96) {
    float* cdst = (float*)(smem + 32768) + buf * 416;  // 4*104
    int base = i0 - jb - 63 + tid;
#pragma unroll
    for (int ph = 0; ph < 4; ++ph) {
      int src = base + ph;
      src = src > S_ - 1 ? S_ - 1 : src;
      async4(cumn + src, cdst + ph * 104 + tid);
    }
  }
}

__global__ __launch_bounds__(256, 2)
void fa_kernel(const bf16* __restrict__ q, const bf16* __restrict__ k,
               const bf16* __restrict__ vt, const float* __restrict__ cum,
               bf16* __restrict__ mix) {
  __shared__ char smem[36224] __attribute__((aligned(16)));
  float* combL = (float*)(smem + 36096);        // [2 rg][16]

  const int tid = threadIdx.x, lane = tid & 63, w = tid >> 6;  // w: 0..3
  const int lr = lane & 15, lq = lane >> 4;
  const int jh = w & 1, rg = w >> 1;            // j-half (32 cols), row-group

  const int L = blockIdx.x;                     // 0..1023
  const int xcd = L & 7, slot = L >> 3;         // slot 0..127
  const int bn = xcd + 8 * (slot & 3);          // 4 heads per XCD
  const int p = slot >> 2;                      // pair index 0..31
  const int n = bn & (NH - 1);
  const int b = bn >> 4;
  const float* cumn = cum + (size_t)n * CUMROW + CUMPAD;

  const int T0 = 63 - p;                        // heavy tile (32-row)
  const int T1 = p;                             // light tile
  const int nu0 = (T0 + 2) >> 1;                // units in tile 0

  // all-ones B fragment for the l row-sum MFMA
  bf16x8 ones;
#pragma unroll
  for (int u = 0; u < 8; ++u) ones[u] = (short)0x3F80;
  const f32x4 fz = {0.f, 0.f, 0.f, 0.f};

  // permuted-K swizzle key (independent of kd/nt2/jh)
  const int kkey = (lr & 3) | (((lr >> 2) & 1) << 2);

  bf16x8 qf[2];                                 // [kd]
  f32x4 oacc[4];                                // [dt]
  f32x4 lacc;

  // prologue: stage unit 0 (tile T0, jt 0) into buf 0
  fa_stage(k, vt, cumn, smem, bn, T0 * 32, 0, 0, tid);

  int jt = 0, i0 = T0 * 32, nu = nu0;

  for (int g = 0; g < 33; ++g) {
    const int bsel = g & 1;
    const char* kb = smem + bsel * 16384;
    const char* vb = kb + 8192;
    const float* cumB = (const float*)(smem + 32768) + bsel * 416;
    const int jb = jt * 64;
    const bool diag = (jt == nu - 1);           // last unit of this tile
    const int doff = i0 - jb;                   // diag: 0 or 32; else >=64

    __syncthreads();   // staged data for g visible; buf^1 prior reads done

    // prefetch unit g+1 into the other buffer (flies during this compute)
    if (g + 1 < 33) {
      int gn = g + 1, tin, jtn;
      if (gn < nu0) { tin = T0; jtn = gn; }
      else          { tin = T1; jtn = gn - nu0; }
      fa_stage(k, vt, cumn, smem, bn, tin * 32, jtn * 64, bsel ^ 1, tid);
    }

    if (jt == 0) {
      // new tile: load Q fragments (B-operand for S^T = K*Q^T), reset acc
      const bf16* qbase = q + ((size_t)bn * S_ + i0 + rg * 16) * DH;
#pragma unroll
      for (int kd = 0; kd < 2; ++kd)
        qf[kd] = *(const bf16x8*)(qbase + lr * DH + kd * 32 + lq * 8);
      lacc = fz;
#pragma unroll
      for (int dt = 0; dt < 4; ++dt) oacc[dt] = fz;
    }

    // S^T = K * Q^T with PERMUTED K rows over this wave's 32-col chunk.
    // A-row lr of MFMA nt2 loads krow = jh*32 + (lr>>2)*8 + nt2*4 + (lr&3),
    // so C position (lq*4+r) holds j = jh*32 + lq*8 + nt2*4 + r — the PV
    // A-fragment layout.
    f32x4 sa[2] = {};
#pragma unroll
    for (int kd = 0; kd < 2; ++kd)
#pragma unroll
      for (int nt2 = 0; nt2 < 2; ++nt2) {
        int krow = jh * 32 + ((lr >> 2) << 3) + nt2 * 4 + (lr & 3);
        bf16x8 kf = *(const bf16x8*)(kb + krow * 128 +
                        (((kd * 4 + lq) ^ kkey) << 4));
        sa[nt2] = MFMA16(kf, qf[kd], sa[nt2]);
      }

    // p = exp2(s*SCALE2 + cum[i-j]) straight into the PV A-fragment.
    // One b128 bias read per reg-quad: Xm3 = 60+iloc-jl in [0,91];
    // cv[m] = win[Xm3+m]; bias(r) = cv[3-r].
    const int iloc = rg * 16 + lr;              // 0..31
    bf16x8 pf;
#pragma unroll
    for (int nt2 = 0; nt2 < 2; ++nt2) {
      int jl = jh * 32 + lq * 8 + nt2 * 4;
      int Xm3 = 60 + iloc - jl;
      int ph = Xm3 & 3, b0 = Xm3 & ~3;
      f32x4 cv = *(const f32x4*)(cumB + ph * 104 + b0);
      if (!diag) {
#pragma unroll
        for (int r = 0; r < 4; ++r)
          pf[nt2 * 4 + r] = bf16bits(exp2f(sa[nt2][r] * SCALE2 + cv[3 - r]));
      } else {
#pragma unroll
        for (int r = 0; r < 4; ++r) {
          float pv = (doff + iloc - jl - r >= 0)
                         ? exp2f(sa[nt2][r] * SCALE2 + cv[3 - r])
                         : 0.f;
          pf[nt2 * 4 + r] = bf16bits(pv);
        }
      }
    }

    // O += P V; l += P 1 — pf straight from registers.
    lacc = MFMA16(pf, ones, lacc);
#pragma unroll
    for (int dt = 0; dt < 4; ++dt) {
      int vrow = dt * 16 + lr;
      bf16x8 vf = *(const bf16x8*)(vb + vrow * 128 +
                      (((jh * 4 + lq) ^ (vrow & 7)) << 4));
      oacc[dt] = MFMA16(pf, vf, oacc[dt]);
    }

    if (diag) {
      // tile end: combine the 2 j-halves per rg (additive — no-max exp2
      // softmax) through the consumed K/V buffer (per rg: 4KB).
      __syncthreads();   // all reads of buf bsel complete
      f32x4* scrq = (f32x4*)(smem + bsel * 16384) + rg * 256;
      if (jh == 1) {
#pragma unroll
        for (int dt = 0; dt < 4; ++dt)
          scrq[dt * 64 + lane] = oacc[dt];
        if (lr == 0)
#pragma unroll
          for (int r = 0; r < 4; ++r)
            combL[rg * 16 + lq * 4 + r] = lacc[r];
      }
      __syncthreads();   // partials visible
      if (jh == 0) {
#pragma unroll
        for (int dt = 0; dt < 4; ++dt)
          oacc[dt] += scrq[dt * 64 + lane];
#pragma unroll
        for (int r = 0; r < 4; ++r)
          lacc[r] += combL[rg * 16 + lq * 4 + r];
        // store mix[b][s][n][d] for this rg's 16 rows
#pragma unroll
        for (int dt = 0; dt < 4; ++dt)
#pragma unroll
          for (int r = 0; r < 4; ++r) {
            int i = i0 + rg * 16 + lq * 4 + r;
            int d = dt * 16 + lr;
            mix[((size_t)(b * S_ + i) * NH + n) * DH + d] =
                __float2bfloat16(oacc[dt][r] / lacc[r]);
          }
      }
      jt = 0; i0 = T1 * 32; nu = (T1 + 2) >> 1;  // switch to light tile
    } else {
      ++jt;
    }
  }
}

// ---------------------------------------------------------------------------
extern "C" void kernel_launch(void* const* d_in, const int* in_sizes, int n_in,
                              void* d_out, int out_size, void* d_ws, size_t ws_size,
                              hipStream_t stream) {
  const float* x     = (const float*)d_in[0];   // [B,S,H] f32
  const float* qkv   = (const float*)d_in[1];   // [H,3,N,D] f32 == [1024][3072]
  const float* out_w = (const float*)d_in[2];   // [N,D,H] f32   == [1024][1024]
  const float* rpe   = (const float*)d_in[3];   // [N,S] f32
  float* out = (float*)d_out;                   // [B,S,H] f32

  char* ws = (char*)d_ws;
  bf16* qkvT  = (bf16*)(ws + 0);          // [3072][1024] bf16   6291456 B
  bf16* outwT = (bf16*)(ws + 6291456);    // [1024][1024] bf16   2097152 B
  bf16* xb    = (bf16*)(ws + 8388608);    // [4096][1024] bf16   8388608 B
  bf16* qb    = (bf16*)(ws + 16777216);   // [bn][S][D]          8388608 B
  bf16* kb    = (bf16*)(ws + 25165824);   // [bn][S][D]          8388608 B
  bf16* vtb   = (bf16*)(ws + 33554432);   // [bn][D][S]          8388608 B
  bf16* mixb  = (bf16*)(ws + 41943040);   // [b][s][n][d]        8388608 B
  float* cum  = (float*)(ws + 50331648);  // [N][CUMROW] f32      139520 B

  // 1. fused prep: convert x, transpose+convert weights, padded rpe cumsum
  prep<<<8208, 256, 0, stream>>>(x, xb, qkv, qkvT, out_w, outwT, rpe, cum);
  // 2. QKV projection (V written pre-transposed; 768 blocks = 3/CU)
  gemm_bt<0><<<dim3(3072 / 128, 4096 / 128), 256, 0, stream>>>(xb, qkvT, qb, kb, vtb, nullptr);
  // 3. attention: 1024 blocks x 256 threads, 4 blocks/CU = 16 waves/CU,
  //    32-row tiles, 64-col units, pair {63-p, p} = exactly 33 units each
  fa_kernel<<<1024, 256, 0, stream>>>(qb, kb, vtb, cum, mixb);
  // 4. output projection (f32 out; 128x64 tiles -> 512 blocks = 2/CU)
  gemm_bt<1><<<dim3(1024 / 64, 4096 / 128), 256, 0, stream>>>(mixb, outwT, nullptr, nullptr, nullptr, out);
}

// Round 14
// 177.421 us; speedup vs baseline: 1.0665x; 1.0086x over previous
//
#include <hip/hip_runtime.h>
#include <hip/hip_bf16.h>
#include <cstdint>
#include <cstddef>

// Problem constants
#define B_   2
#define S_   2048
#define H_   1024
#define NH   16
#define DH   64
#define LOG2E 1.4426950408889634f
#define SCALE2 (0.125f * LOG2E)   // D^-0.5 * log2(e): softmax done in exp2 domain
#define CUMPAD 132                // zero-pad floats before cum row
#define CUMROW (CUMPAD + S_)      // 2180 floats per head row

typedef __hip_bfloat16 bf16;
typedef short bf16x8 __attribute__((ext_vector_type(8)));   // 8 bf16 in 4 VGPRs
typedef float f32x4 __attribute__((ext_vector_type(4)));

#define MFMA16(a, b, c) __builtin_amdgcn_mfma_f32_16x16x32_bf16((a), (b), (c), 0, 0, 0)

__device__ __forceinline__ void async16(const void* g, void* l) {
  __builtin_amdgcn_global_load_lds(
      (const __attribute__((address_space(1))) void*)g,
      (__attribute__((address_space(3))) void*)l,
      16, 0, 0);
}
__device__ __forceinline__ void async4(const void* g, void* l) {
  __builtin_amdgcn_global_load_lds(
      (const __attribute__((address_space(1))) void*)g,
      (__attribute__((address_space(3))) void*)l,
      4, 0, 0);
}

__device__ __forceinline__ short bf16bits(float v) {
  bf16 t = __float2bfloat16(v);
  return *reinterpret_cast<short*>(&t);
}

// ---------------------------------------------------------------------------
// Fused prep kernel, R14 (grid 6160):
//  blocks [0,4096):     convert x f32->bf16 (unchanged)
//  blocks [4096,5632):  qkv transpose v2: 64x32 tiles, b128 coalesced stores
//  blocks [5632,6144):  outw transpose v2
//  blocks [6144,6160):  rpe cumsum (padded row, xLOG2E)
// Transpose v2: old stores were scalar bf16, 64B per wave-row (half a line).
// New: LDS tile [32 dst-rows][72], write phase emits one uint4 (8 bf16) per
// lane, 8 lanes per 128B dst row — fully coalesced.
// ---------------------------------------------------------------------------
__device__ __forceinline__ void tr64(const float* __restrict__ src,
                                     bf16* __restrict__ dst, int R, int C,
                                     int c0, int r0, bf16 (*tile)[72], int tid) {
  int tx = tid & 31, ty = tid >> 5;   // 32 cols x 8 rows per iter
#pragma unroll
  for (int i = 0; i < 64; i += 8)
    tile[tx][ty + i] = __float2bfloat16(src[(size_t)(r0 + ty + i) * C + c0 + tx]);
  __syncthreads();
  int c = tid >> 3, h = tid & 7;      // 32 dst rows x 8 chunks
  *(uint4*)(dst + (size_t)(c0 + c) * R + r0 + h * 8) = *(const uint4*)(&tile[c][h * 8]);
}

__global__ __launch_bounds__(256)
void prep(const float* __restrict__ x, bf16* __restrict__ xb,
          const float* __restrict__ qkv, bf16* __restrict__ qkvT,
          const float* __restrict__ outw, bf16* __restrict__ outwT,
          const float* __restrict__ rpe, float* __restrict__ cum) {
  __shared__ char pm[4608] __attribute__((aligned(16)));
  const int L = blockIdx.x, tid = threadIdx.x;
  if (L < 4096) {
    int i = (L * 256 + tid) * 4;
    float4 v = *(const float4*)(x + i);
    bf16 o[4] = {__float2bfloat16(v.x), __float2bfloat16(v.y),
                 __float2bfloat16(v.z), __float2bfloat16(v.w)};
    *(uint64_t*)(xb + i) = *(const uint64_t*)o;
  } else if (L < 5632) {
    int t = L - 4096;                 // qkv [1024][3072] -> [3072][1024]
    int cx = t % 96, ry = t / 96;     // 96 col-tiles x 16 row-tiles
    tr64(qkv, qkvT, 1024, 3072, cx * 32, ry * 64, (bf16(*)[72])pm, tid);
  } else if (L < 6144) {
    int t = L - 5632;                 // outw [1024][1024] -> [1024][1024]
    int cx = t & 31, ry = t >> 5;     // 32 col-tiles x 16 row-tiles
    tr64(outw, outwT, 1024, 1024, cx * 32, ry * 64, (bf16(*)[72])pm, tid);
  } else {
    // rpe cumsum (scaled by LOG2E) into padded row
    float* ssum = (float*)pm;
    int n = L - 6144;
    float* crow = cum + (size_t)n * CUMROW;
    if (tid < CUMPAD) crow[tid] = 0.f;          // zero the pad
    float loc[8];
    float s = 0.f;
    int base = tid * 8;
#pragma unroll
    for (int u = 0; u < 8; ++u) {
      loc[u] = rpe[n * S_ + base + u];
      s += loc[u];
    }
    ssum[tid] = s;
    __syncthreads();
    float own = s;
    for (int off = 1; off < 256; off <<= 1) {
      float v = (tid >= off) ? ssum[tid - off] : 0.f;
      __syncthreads();
      ssum[tid] += v;
      __syncthreads();
    }
    float run = ssum[tid] - own;   // exclusive prefix of this thread's chunk
#pragma unroll
    for (int u = 0; u < 8; ++u) {
      run += loc[u];
      crow[CUMPAD + base + u] = run * LOG2E;
    }
  }
}

// ---------------------------------------------------------------------------
// GEMM, R14: R8 structure + T1 XCD-CHUNKED TILE SWIZZLE. Default x-major
// dispatch round-robins same-A-panel blocks across all 8 XCDs -> each XCD
// fetches ~all of A+B (~14MB). Remap (bijective) so XCD r = L%8 owns a
// contiguous tile rectangle: MODE0 8m x 12n (fetch ~5MB/XCD), MODE1 8m x 8n.
// Pure permutation of tiles — correctness-independent of the XCD mapping.
// ---------------------------------------------------------------------------
template <int MODE>
__global__ __launch_bounds__(256, MODE == 0 ? 3 : 2)
void gemm_bt(const bf16* __restrict__ A, const bf16* __restrict__ Bt,
             bf16* __restrict__ C0, bf16* __restrict__ C1, bf16* __restrict__ C2,
             float* __restrict__ F0) {
  constexpr int NT = (MODE == 0) ? 4 : 2;     // n-subtiles per wave
  constexpr int NB = NT * 32;                 // block n-extent: 128 or 64
  constexpr int BUFSZ = 8192 + NB * 64;       // A 8KB + B NB*32*2B
  __shared__ char smem[MODE == 0 ? 36864 : 24576] __attribute__((aligned(16)));
  const int tid = threadIdx.x, lane = tid & 63, w = tid >> 6;
  const int lr = lane & 15, lq = lane >> 4;

  // XCD-chunked tile remap (T1)
  const int Lg = blockIdx.y * (MODE == 0 ? 24 : 16) + blockIdx.x;
  const int rr = Lg & 7, ss = Lg >> 3;
  int m0, n0;
  if (MODE == 0) {                            // 768 blocks: rects 8m x 12n
    m0 = ((rr >> 1) * 8 + ss / 12) * 128;
    n0 = ((rr & 1) * 12 + ss % 12) * 128;
  } else {                                    // 512 blocks: rects 8m x 8n
    m0 = ((rr >> 1) * 8 + (ss >> 3)) * 128;
    n0 = ((rr & 1) * 8 + (ss & 7)) * 64;
  }
  const int wm = (w & 1) * 64, wn = (w >> 1) * (NT * 16);

  f32x4 acc[4][NT] = {};

  auto stage = [&](int buf, int k0) {
    char* dst = smem + buf * BUFSZ;
#pragma unroll
    for (int t = 0; t < 2; ++t) {
      int c = t * 256 + tid;
      int row = c >> 2, ch = c & 3;
      int k8 = (ch ^ ((row >> 1) & 3)) * 8;
      async16(A + (size_t)(m0 + row) * 1024 + k0 + k8, dst + c * 16);
    }
#pragma unroll
    for (int t = 0; t < NB / 64; ++t) {
      int c = t * 256 + tid;
      int row = c >> 2, ch = c & 3;
      int k8 = (ch ^ ((row >> 1) & 3)) * 8;
      async16(Bt + (size_t)(n0 + row) * 1024 + k0 + k8, dst + 8192 + c * 16);
    }
  };

  stage(0, 0);

  for (int s = 0; s < 32; ++s) {
    const int bsel = s & 1;
    __syncthreads();
    if (s + 1 < 32) stage(bsel ^ 1, (s + 1) * 32);

    const bf16* As = (const bf16*)(smem + bsel * BUFSZ);
    const bf16* Bs = (const bf16*)(smem + bsel * BUFSZ + 8192);
    bf16x8 af[4], bfr[NT];
#pragma unroll
    for (int mt = 0; mt < 4; ++mt) {
      int row = wm + mt * 16 + lr;
      af[mt] = *(const bf16x8*)(As + row * 32 + ((lq ^ ((row >> 1) & 3)) << 3));
    }
#pragma unroll
    for (int nt = 0; nt < NT; ++nt) {
      int row = wn + nt * 16 + lr;
      bfr[nt] = *(const bf16x8*)(Bs + row * 32 + ((lq ^ ((row >> 1) & 3)) << 3));
    }
#pragma unroll
    for (int mt = 0; mt < 4; ++mt)
#pragma unroll
      for (int nt = 0; nt < NT; ++nt)
        acc[mt][nt] = MFMA16(af[mt], bfr[nt], acc[mt][nt]);
  }

  if (MODE == 0) {
    __syncthreads();   // all As/Bs reads done; reuse LDS for epilogue tiles
    bf16* E = (bf16*)smem + w * (64 * 72);   // wave-private [64][72]
    const int cbase = n0 + wn;               // 64-aligned
    const int mm = cbase >> 10, nn = (cbase >> 6) & 15;
    const int bb = (m0 + wm) >> 11;
    const int sbase = (m0 + wm) & 2047;
    if (mm < 2) {
#pragma unroll
      for (int mt = 0; mt < 4; ++mt)
#pragma unroll
        for (int nt = 0; nt < 4; ++nt)
#pragma unroll
          for (int r = 0; r < 4; ++r)
            E[(mt * 16 + lq * 4 + r) * 72 + nt * 16 + lr] =
                __float2bfloat16(acc[mt][nt][r]);
      bf16* dst = (mm == 0 ? C0 : C1) +
                  ((size_t)(bb * NH + nn) * S_ + sbase) * DH;
#pragma unroll
      for (int it = 0; it < 8; ++it) {
        int c = it * 64 + lane;
        int rw = c >> 3, c8 = c & 7;
        *(uint4*)(dst + (size_t)rw * DH + c8 * 8) =
            *(const uint4*)(E + rw * 72 + c8 * 8);
      }
    } else {
#pragma unroll
      for (int mt = 0; mt < 4; ++mt)
#pragma unroll
        for (int nt = 0; nt < 4; ++nt)
#pragma unroll
          for (int r = 0; r < 4; ++r)
            E[(nt * 16 + lr) * 72 + mt * 16 + lq * 4 + r] =
                __float2bfloat16(acc[mt][nt][r]);
      bf16* dst = C2 + (size_t)(bb * NH + nn) * DH * S_;
#pragma unroll
      for (int it = 0; it < 8; ++it) {
        int c = it * 64 + lane;
        int dr = c >> 3, c8 = c & 7;
        *(uint4*)(dst + (size_t)dr * S_ + sbase + c8 * 8) =
            *(const uint4*)(E + dr * 72 + c8 * 8);
      }
    }
  } else {
#pragma unroll
    for (int mt = 0; mt < 4; ++mt)
#pragma unroll
      for (int nt = 0; nt < NT; ++nt)
#pragma unroll
        for (int r = 0; r < 4; ++r) {
          int rM = m0 + wm + mt * 16 + lq * 4 + r;
          int cN = n0 + wn + nt * 16 + lr;
          F0[(size_t)rM * 1024 + cN] = acc[mt][nt][r];
        }
  }
}

// ---------------------------------------------------------------------------
// Flash attention — UNCHANGED from R13 (the control this round).
// 32-row Q-tiles, 64-col units, pair {63-p, p} = 33 units, 1024 blocks =
// 4/CU = 16 waves/CU, 52 VGPR (no spills), in-reg P via permuted K rows,
// dbuf + prefetch-after-barrier, LDS 4-phase bias windows (stride 104).
// LDS: K/V dbuf [0,32768); cum [2][4][104] f32 [32768,36096);
//      combL [2][16] f32 [36096,36224). 36224 x 4 blocks/CU <= 160 KB.
// ---------------------------------------------------------------------------
__device__ __forceinline__ void fa_stage(const bf16* __restrict__ k,
                                         const bf16* __restrict__ vt,
                                         const float* __restrict__ cumn,
                                         char* smem, int bn, int i0, int jb,
                                         int buf, int tid) {
  char* dst = smem + buf * 16384;
  // K tile: rows jb..jb+63 (128B each, 8 chunks); slot (row,ch) holds
  // global chunk ch^kk(row), kk = (row&3)|((row>>1)&4). 512 chunks.
  const char* ksrc = (const char*)(k + ((size_t)bn * S_ + jb) * DH);
#pragma unroll
  for (int t = 0; t < 2; ++t) {
    int c = t * 256 + tid;
    int row = c >> 3, ch = c & 7;
    int cs = ch ^ ((row & 3) | ((row >> 1) & 4));
    async16(ksrc + row * 128 + cs * 16, dst + c * 16);
  }
  // Vt tile: d rows 0..63, cols jb..jb+63 (128B, 8 chunks); slot (d,ch)
  // holds global chunk ch^(d&7). 512 chunks.
  const char* vsrc = (const char*)(vt + (size_t)bn * DH * S_);
#pragma unroll
  for (int t = 0; t < 2; ++t) {
    int c = t * 256 + tid;
    int row = c >> 3, ch = c & 7;             // row = d index
    int cs = ch ^ (row & 7);
    async16(vsrc + (size_t)row * (S_ * 2) + jb * 2 + cs * 16,
            dst + 8192 + c * 16);
  }
  // cum windows: win[t] = cumn[i0-jb-63+t] (negatives land in the zero
  // pad; clamp high only). 4 phases, stride 104 (== 8 mod 32 banks).
  if (tid < 96) {
    float* cdst = (float*)(smem + 32768) + buf * 416;  // 4*104
    int base = i0 - jb - 63 + tid;
#pragma unroll
    for (int ph = 0; ph < 4; ++ph) {
      int src = base + ph;
      src = src > S_ - 1 ? S_ - 1 : src;
      async4(cumn + src, cdst + ph * 104 + tid);
    }
  }
}

__global__ __launch_bounds__(256, 2)
void fa_kernel(const bf16* __restrict__ q, const bf16* __restrict__ k,
               const bf16* __restrict__ vt, const float* __restrict__ cum,
               bf16* __restrict__ mix) {
  __shared__ char smem[36224] __attribute__((aligned(16)));
  float* combL = (float*)(smem + 36096);        // [2 rg][16]

  const int tid = threadIdx.x, lane = tid & 63, w = tid >> 6;  // w: 0..3
  const int lr = lane & 15, lq = lane >> 4;
  const int jh = w & 1, rg = w >> 1;            // j-half (32 cols), row-group

  const int L = blockIdx.x;                     // 0..1023
  const int xcd = L & 7, slot = L >> 3;         // slot 0..127
  const int bn = xcd + 8 * (slot & 3);          // 4 heads per XCD
  const int p = slot >> 2;                      // pair index 0..31
  const int n = bn & (NH - 1);
  const int b = bn >> 4;
  const float* cumn = cum + (size_t)n * CUMROW + CUMPAD;

  const int T0 = 63 - p;                        // heavy tile (32-row)
  const int T1 = p;                             // light tile
  const int nu0 = (T0 + 2) >> 1;                // units in tile 0

  // all-ones B fragment for the l row-sum MFMA
  bf16x8 ones;
#pragma unroll
  for (int u = 0; u < 8; ++u) ones[u] = (short)0x3F80;
  const f32x4 fz = {0.f, 0.f, 0.f, 0.f};

  // permuted-K swizzle key (independent of kd/nt2/jh)
  const int kkey = (lr & 3) | (((lr >> 2) & 1) << 2);

  bf16x8 qf[2];                                 // [kd]
  f32x4 oacc[4];                                // [dt]
  f32x4 lacc;

  // prologue: stage unit 0 (tile T0, jt 0) into buf 0
  fa_stage(k, vt, cumn, smem, bn, T0 * 32, 0, 0, tid);

  int jt = 0, i0 = T0 * 32, nu = nu0;

  for (int g = 0; g < 33; ++g) {
    const int bsel = g & 1;
    const char* kb = smem + bsel * 16384;
    const char* vb = kb + 8192;
    const float* cumB = (const float*)(smem + 32768) + bsel * 416;
    const int jb = jt * 64;
    const bool diag = (jt == nu - 1);           // last unit of this tile
    const int doff = i0 - jb;                   // diag: 0 or 32; else >=64

    __syncthreads();   // staged data for g visible; buf^1 prior reads done

    // prefetch unit g+1 into the other buffer (flies during this compute)
    if (g + 1 < 33) {
      int gn = g + 1, tin, jtn;
      if (gn < nu0) { tin = T0; jtn = gn; }
      else          { tin = T1; jtn = gn - nu0; }
      fa_stage(k, vt, cumn, smem, bn, tin * 32, jtn * 64, bsel ^ 1, tid);
    }

    if (jt == 0) {
      // new tile: load Q fragments (B-operand for S^T = K*Q^T), reset acc
      const bf16* qbase = q + ((size_t)bn * S_ + i0 + rg * 16) * DH;
#pragma unroll
      for (int kd = 0; kd < 2; ++kd)
        qf[kd] = *(const bf16x8*)(qbase + lr * DH + kd * 32 + lq * 8);
      lacc = fz;
#pragma unroll
      for (int dt = 0; dt < 4; ++dt) oacc[dt] = fz;
    }

    // S^T = K * Q^T with PERMUTED K rows over this wave's 32-col chunk.
    // A-row lr of MFMA nt2 loads krow = jh*32 + (lr>>2)*8 + nt2*4 + (lr&3),
    // so C position (lq*4+r) holds j = jh*32 + lq*8 + nt2*4 + r — the PV
    // A-fragment layout.
    f32x4 sa[2] = {};
#pragma unroll
    for (int kd = 0; kd < 2; ++kd)
#pragma unroll
      for (int nt2 = 0; nt2 < 2; ++nt2) {
        int krow = jh * 32 + ((lr >> 2) << 3) + nt2 * 4 + (lr & 3);
        bf16x8 kf = *(const bf16x8*)(kb + krow * 128 +
                        (((kd * 4 + lq) ^ kkey) << 4));
        sa[nt2] = MFMA16(kf, qf[kd], sa[nt2]);
      }

    // p = exp2(s*SCALE2 + cum[i-j]) straight into the PV A-fragment.
    // One b128 bias read per reg-quad: Xm3 = 60+iloc-jl in [0,91];
    // cv[m] = win[Xm3+m]; bias(r) = cv[3-r].
    const int iloc = rg * 16 + lr;              // 0..31
    bf16x8 pf;
#pragma unroll
    for (int nt2 = 0; nt2 < 2; ++nt2) {
      int jl = jh * 32 + lq * 8 + nt2 * 4;
      int Xm3 = 60 + iloc - jl;
      int ph = Xm3 & 3, b0 = Xm3 & ~3;
      f32x4 cv = *(const f32x4*)(cumB + ph * 104 + b0);
      if (!diag) {
#pragma unroll
        for (int r = 0; r < 4; ++r)
          pf[nt2 * 4 + r] = bf16bits(exp2f(sa[nt2][r] * SCALE2 + cv[3 - r]));
      } else {
#pragma unroll
        for (int r = 0; r < 4; ++r) {
          float pv = (doff + iloc - jl - r >= 0)
                         ? exp2f(sa[nt2][r] * SCALE2 + cv[3 - r])
                         : 0.f;
          pf[nt2 * 4 + r] = bf16bits(pv);
        }
      }
    }

    // O += P V; l += P 1 — pf straight from registers.
    lacc = MFMA16(pf, ones, lacc);
#pragma unroll
    for (int dt = 0; dt < 4; ++dt) {
      int vrow = dt * 16 + lr;
      bf16x8 vf = *(const bf16x8*)(vb + vrow * 128 +
                      (((jh * 4 + lq) ^ (vrow & 7)) << 4));
      oacc[dt] = MFMA16(pf, vf, oacc[dt]);
    }

    if (diag) {
      // tile end: combine the 2 j-halves per rg (additive — no-max exp2
      // softmax) through the consumed K/V buffer (per rg: 4KB).
      __syncthreads();   // all reads of buf bsel complete
      f32x4* scrq = (f32x4*)(smem + bsel * 16384) + rg * 256;
      if (jh == 1) {
#pragma unroll
        for (int dt = 0; dt < 4; ++dt)
          scrq[dt * 64 + lane] = oacc[dt];
        if (lr == 0)
#pragma unroll
          for (int r = 0; r < 4; ++r)
            combL[rg * 16 + lq * 4 + r] = lacc[r];
      }
      __syncthreads();   // partials visible
      if (jh == 0) {
#pragma unroll
        for (int dt = 0; dt < 4; ++dt)
          oacc[dt] += scrq[dt * 64 + lane];
#pragma unroll
        for (int r = 0; r < 4; ++r)
          lacc[r] += combL[rg * 16 + lq * 4 + r];
        // store mix[b][s][n][d] for this rg's 16 rows
#pragma unroll
        for (int dt = 0; dt < 4; ++dt)
#pragma unroll
          for (int r = 0; r < 4; ++r) {
            int i = i0 + rg * 16 + lq * 4 + r;
            int d = dt * 16 + lr;
            mix[((size_t)(b * S_ + i) * NH + n) * DH + d] =
                __float2bfloat16(oacc[dt][r] / lacc[r]);
          }
      }
      jt = 0; i0 = T1 * 32; nu = (T1 + 2) >> 1;  // switch to light tile
    } else {
      ++jt;
    }
  }
}

// ---------------------------------------------------------------------------
extern "C" void kernel_launch(void* const* d_in, const int* in_sizes, int n_in,
                              void* d_out, int out_size, void* d_ws, size_t ws_size,
                              hipStream_t stream) {
  const float* x     = (const float*)d_in[0];   // [B,S,H] f32
  const float* qkv   = (const float*)d_in[1];   // [H,3,N,D] f32 == [1024][3072]
  const float* out_w = (const float*)d_in[2];   // [N,D,H] f32   == [1024][1024]
  const float* rpe   = (const float*)d_in[3];   // [N,S] f32
  float* out = (float*)d_out;                   // [B,S,H] f32

  char* ws = (char*)d_ws;
  bf16* qkvT  = (bf16*)(ws + 0);          // [3072][1024] bf16   6291456 B
  bf16* outwT = (bf16*)(ws + 6291456);    // [1024][1024] bf16   2097152 B
  bf16* xb    = (bf16*)(ws + 8388608);    // [4096][1024] bf16   8388608 B
  bf16* qb    = (bf16*)(ws + 16777216);   // [bn][S][D]          8388608 B
  bf16* kb    = (bf16*)(ws + 25165824);   // [bn][S][D]          8388608 B
  bf16* vtb   = (bf16*)(ws + 33554432);   // [bn][D][S]          8388608 B
  bf16* mixb  = (bf16*)(ws + 41943040);   // [b][s][n][d]        8388608 B
  float* cum  = (float*)(ws + 50331648);  // [N][CUMROW] f32      139520 B

  // 1. fused prep: convert x, coalesced transposes, padded rpe cumsum
  prep<<<6160, 256, 0, stream>>>(x, xb, qkv, qkvT, out_w, outwT, rpe, cum);
  // 2. QKV projection (XCD-chunked tiles; V pre-transposed; 768 blocks)
  gemm_bt<0><<<dim3(3072 / 128, 4096 / 128), 256, 0, stream>>>(xb, qkvT, qb, kb, vtb, nullptr);
  // 3. attention — unchanged R13 (control): 1024 blocks, 16 waves/CU
  fa_kernel<<<1024, 256, 0, stream>>>(qb, kb, vtb, cum, mixb);
  // 4. output projection (XCD-chunked tiles; f32 out; 512 blocks = 2/CU)
  gemm_bt<1><<<dim3(1024 / 64, 4096 / 128), 256, 0, stream>>>(mixb, outwT, nullptr, nullptr, nullptr, out);
}